// Round 5
// baseline (1826.109 us; speedup 1.0000x reference)
//
#include <hip/hip_runtime.h>
#include <cstddef>

// ---------------------------------------------------------------------------
// GCN: out = relu(Â relu(Â relu(Â (x W0)) W1) W2),  Â = D^-1/2 (A+I) D^-1/2
// R5: bucketed edge layout (32 nodes/bucket, 3125 buckets) -> fill scatter has
// only 3125 active write tails (no write amplification); aggregation scatters
// into an LDS accumulator per bucket (ds_add_f32), fused self-loop + ReLU.
// ---------------------------------------------------------------------------

constexpr int BK = 32;  // nodes per bucket (N = 100000 = 3125 * 32)

struct EdgeRec { unsigned int key; float norm; };  // key = (dstLocal<<27) | src

__global__ void deg_kernel(const int* __restrict__ dst, int E, int* __restrict__ cnt) {
    int i = blockIdx.x * blockDim.x + threadIdx.x;
    if (i < E) atomicAdd(&cnt[dst[i]], 1);
}

__global__ void dinv_kernel(const int* __restrict__ cnt, float* __restrict__ dinv, int N) {
    int i = blockIdx.x * blockDim.x + threadIdx.x;
    if (i < N) dinv[i] = rsqrtf((float)cnt[i] + 1.0f);  // +1 self-loop; deg>0 always
}

// per-bucket edge counts derived from per-node counts (no extra atomics)
__global__ void bucketsum_kernel(const int* __restrict__ cnt, int* __restrict__ bcnt,
                                 int nb, int N) {
    int b = blockIdx.x * blockDim.x + threadIdx.x;
    if (b < nb) {
        int s = 0, base = b * BK;
#pragma unroll
        for (int i = 0; i < BK; ++i) {
            int idx = base + i;
            s += (idx < N) ? cnt[idx] : 0;
        }
        bcnt[b] = s;
    }
}

// ---- exclusive scan of bcnt[nb] -> bptr[nb] (nb = 3125 fits one chunk) ----
constexpr int SCAN_ITEMS = 16;
constexpr int SCAN_CHUNK = 256 * SCAN_ITEMS;  // 4096

__global__ __launch_bounds__(256) void scan1_kernel(const int* __restrict__ cnt,
                                                    int* __restrict__ rowptr,
                                                    int* __restrict__ blockSums, int N) {
    __shared__ int sh[256];
    int tbase = blockIdx.x * SCAN_CHUNK + threadIdx.x * SCAN_ITEMS;
    int vals[SCAN_ITEMS];
    int tsum = 0;
#pragma unroll
    for (int j = 0; j < SCAN_ITEMS; ++j) {
        int idx = tbase + j;
        int v = (idx < N) ? cnt[idx] : 0;
        vals[j] = tsum;
        tsum += v;
    }
    sh[threadIdx.x] = tsum;
    __syncthreads();
    for (int off = 1; off < 256; off <<= 1) {
        int v = (threadIdx.x >= off) ? sh[threadIdx.x - off] : 0;
        __syncthreads();
        sh[threadIdx.x] += v;
        __syncthreads();
    }
    int texcl = sh[threadIdx.x] - tsum;
    if (threadIdx.x == 255) blockSums[blockIdx.x] = sh[255];
#pragma unroll
    for (int j = 0; j < SCAN_ITEMS; ++j) {
        int idx = tbase + j;
        if (idx < N) rowptr[idx] = texcl + vals[j];
    }
}

__global__ void scan2_kernel(int* __restrict__ blockSums, int nb) {
    if (threadIdx.x == 0 && blockIdx.x == 0) {
        int run = 0;
        for (int i = 0; i < nb; ++i) { int v = blockSums[i]; blockSums[i] = run; run += v; }
    }
}

__global__ __launch_bounds__(256) void scan3_kernel(int* __restrict__ ptr,
                                                    int* __restrict__ cursor,
                                                    const int* __restrict__ blockSums,
                                                    int n, int E) {
    int idx = blockIdx.x * blockDim.x + threadIdx.x;
    if (idx < n) {
        int r = ptr[idx] + blockSums[idx / SCAN_CHUNK];
        ptr[idx] = r;
        cursor[idx] = r;
    }
    if (idx == 0) ptr[n] = E;
}

__global__ void fill_kernel(const int* __restrict__ src, const int* __restrict__ dst,
                            const float* __restrict__ dinv, int* __restrict__ cursor,
                            EdgeRec* __restrict__ rec, int E) {
    int e = blockIdx.x * blockDim.x + threadIdx.x;
    if (e < E) {
        int s = src[e], d = dst[e];
        int slot = atomicAdd(&cursor[d / BK], 1);
        EdgeRec r;
        r.key  = ((unsigned)(d & (BK - 1)) << 27) | (unsigned)s;
        r.norm = dinv[s] * dinv[d];
        rec[slot] = r;
    }
}

// ---------------------------------------------------------------------------
// Register-tiled GEMM: A[N,K] @ W[K,M] -> out[N,M].
// Block = 256 thr = 16x16 grid, 4x4 outputs/thread => 64 rows x 64 cols.
// ---------------------------------------------------------------------------
template <int K, int M>
__global__ __launch_bounds__(256) void gemm_kernel(const float* __restrict__ A,
                                                   const float* __restrict__ W,
                                                   float* __restrict__ out, int N) {
    constexpr int KC = 64;
    constexpr int SA = 68;
    __shared__ float Ws[K * M];
    __shared__ float As[KC * SA];   // As[k][row]
    for (int i = threadIdx.x; i < K * M; i += 256) Ws[i] = W[i];

    const int tr = threadIdx.x & 15;
    const int tc = threadIdx.x >> 4;
    const int r0 = tr * 4, c0 = tc * 4;
    const int row0 = blockIdx.x * 64;
    const bool colAct = (c0 < M);

    float acc[4][4] = {};

    for (int k0 = 0; k0 < K; k0 += KC) {
        __syncthreads();
        {
            const int kq = threadIdx.x & 15;
            const int rr = threadIdx.x >> 4;
#pragma unroll
            for (int p = 0; p < 4; ++p) {
                int row = rr + p * 16;
                int grow = row0 + row;
                float4 v = make_float4(0.f, 0.f, 0.f, 0.f);
                if (grow < N)
                    v = *reinterpret_cast<const float4*>(&A[(size_t)grow * K + k0 + kq * 4]);
                As[(kq * 4 + 0) * SA + row] = v.x;
                As[(kq * 4 + 1) * SA + row] = v.y;
                As[(kq * 4 + 2) * SA + row] = v.z;
                As[(kq * 4 + 3) * SA + row] = v.w;
            }
        }
        __syncthreads();
        if (colAct) {
#pragma unroll 8
            for (int kk = 0; kk < KC; ++kk) {
                float4 a = *reinterpret_cast<const float4*>(&As[kk * SA + r0]);
                float4 b = *reinterpret_cast<const float4*>(&Ws[(k0 + kk) * M + c0]);
                acc[0][0] = fmaf(a.x, b.x, acc[0][0]); acc[0][1] = fmaf(a.x, b.y, acc[0][1]);
                acc[0][2] = fmaf(a.x, b.z, acc[0][2]); acc[0][3] = fmaf(a.x, b.w, acc[0][3]);
                acc[1][0] = fmaf(a.y, b.x, acc[1][0]); acc[1][1] = fmaf(a.y, b.y, acc[1][1]);
                acc[1][2] = fmaf(a.y, b.z, acc[1][2]); acc[1][3] = fmaf(a.y, b.w, acc[1][3]);
                acc[2][0] = fmaf(a.z, b.x, acc[2][0]); acc[2][1] = fmaf(a.z, b.y, acc[2][1]);
                acc[2][2] = fmaf(a.z, b.z, acc[2][2]); acc[2][3] = fmaf(a.z, b.w, acc[2][3]);
                acc[3][0] = fmaf(a.w, b.x, acc[3][0]); acc[3][1] = fmaf(a.w, b.y, acc[3][1]);
                acc[3][2] = fmaf(a.w, b.z, acc[3][2]); acc[3][3] = fmaf(a.w, b.w, acc[3][3]);
            }
        }
    }

    if (colAct) {
#pragma unroll
        for (int i = 0; i < 4; ++i) {
            int grow = row0 + r0 + i;
            if (grow < N) {
                float4 o = make_float4(acc[i][0], acc[i][1], acc[i][2], acc[i][3]);
                *reinterpret_cast<float4*>(&out[(size_t)grow * M + c0]) = o;
            }
        }
    }
}

// ---------------------------------------------------------------------------
// Bucketed aggregation: one block (4 waves) per 32-node bucket. Edges scatter
// into LDS acc[32][D] via ds_add_f32 (lane = feature -> conflict-free).
// Each wave owns a contiguous quarter of the bucket's edge list; 2x unroll.
// Fused self-loop + ReLU finalize with coalesced writes.
// ---------------------------------------------------------------------------
template <int D>
__global__ __launch_bounds__(256) void agg_kernel(const float* __restrict__ t,
                                                  const int* __restrict__ bptr,
                                                  const EdgeRec* __restrict__ rec,
                                                  const float* __restrict__ dinv,
                                                  float* __restrict__ out, int N) {
    __shared__ float acc[BK][D];
    const int b = blockIdx.x;
    const int base = b * BK;
    const int lane = threadIdx.x & 63;
    const int wid  = threadIdx.x >> 6;

    for (int i = threadIdx.x; i < BK * D; i += 256) ((float*)acc)[i] = 0.f;
    __syncthreads();

    const int beg = bptr[b], end = bptr[b + 1];
    const int len = end - beg;
    int wbeg = beg + (len * wid) / 4;
    int wend = beg + (len * (wid + 1)) / 4;

    if (D == 64 || lane < D) {
        int i = wbeg;
        for (; i + 3 < wend; i += 4) {
            EdgeRec r0 = rec[i], r1 = rec[i + 1], r2 = rec[i + 2], r3 = rec[i + 3];
            float v0 = t[(size_t)(r0.key & 0x7FFFFFFu) * D + lane];
            float v1 = t[(size_t)(r1.key & 0x7FFFFFFu) * D + lane];
            float v2 = t[(size_t)(r2.key & 0x7FFFFFFu) * D + lane];
            float v3 = t[(size_t)(r3.key & 0x7FFFFFFu) * D + lane];
            atomicAdd(&acc[r0.key >> 27][lane], v0 * r0.norm);
            atomicAdd(&acc[r1.key >> 27][lane], v1 * r1.norm);
            atomicAdd(&acc[r2.key >> 27][lane], v2 * r2.norm);
            atomicAdd(&acc[r3.key >> 27][lane], v3 * r3.norm);
        }
        for (; i < wend; ++i) {
            EdgeRec r = rec[i];
            float v = t[(size_t)(r.key & 0x7FFFFFFu) * D + lane];
            atomicAdd(&acc[r.key >> 27][lane], v * r.norm);
        }
    }
    __syncthreads();

    // finalize: wave w handles rows w*8 .. w*8+7
#pragma unroll
    for (int j = 0; j < 8; ++j) {
        int l = wid * 8 + j;
        int n = base + l;
        if (n < N && (D == 64 || lane < D)) {
            float di = dinv[n];
            float v = acc[l][lane] + t[(size_t)n * D + lane] * di * di;
            out[(size_t)n * D + lane] = fmaxf(v, 0.f);
        }
    }
}

extern "C" void kernel_launch(void* const* d_in, const int* in_sizes, int n_in,
                              void* d_out, int out_size, void* d_ws, size_t ws_size,
                              hipStream_t stream) {
    const float* x  = (const float*)d_in[0];
    const int*   ei = (const int*)d_in[1];   // [2, E] row-major, int32
    const float* W0 = (const float*)d_in[2]; // [128,64]
    const float* W1 = (const float*)d_in[3]; // [64,64]
    const float* W2 = (const float*)d_in[4]; // [64,40]
    float* out = (float*)d_out;

    const int N = in_sizes[0] / 128;
    const int E = in_sizes[1] / 2;
    const int* src = ei;
    const int* dst = ei + E;
    const int NB = (N + BK - 1) / BK;   // 3125

    char* w = (char*)d_ws;
    size_t off = 0;
    auto alloc = [&](size_t bytes) {
        void* p = w + off;
        off += bytes;
        off = (off + 255) & ~(size_t)255;
        return p;
    };
    int*     cnt    = (int*)alloc((size_t)N * 4);
    float*   dinv   = (float*)alloc((size_t)N * 4);
    int*     bcnt   = (int*)alloc((size_t)NB * 4);
    int*     bptr   = (int*)alloc((size_t)(NB + 1) * 4);
    int*     cursor = (int*)alloc((size_t)NB * 4);
    int*     bsums  = (int*)alloc(4096);
    EdgeRec* rec    = (EdgeRec*)alloc((size_t)E * 8);
    float*   B1     = (float*)alloc((size_t)N * 64 * 4);
    float*   B2     = (float*)alloc((size_t)N * 64 * 4);

    // --- normalization + bucket-CSR build (reused by all 3 layers) ---
    hipMemsetAsync(cnt, 0, (size_t)N * 4, stream);
    deg_kernel<<<(E + 255) / 256, 256, 0, stream>>>(dst, E, cnt);
    dinv_kernel<<<(N + 255) / 256, 256, 0, stream>>>(cnt, dinv, N);
    bucketsum_kernel<<<(NB + 255) / 256, 256, 0, stream>>>(cnt, bcnt, NB, N);
    scan1_kernel<<<(NB + SCAN_CHUNK - 1) / SCAN_CHUNK, 256, 0, stream>>>(bcnt, bptr, bsums, NB);
    scan2_kernel<<<1, 64, 0, stream>>>(bsums, (NB + SCAN_CHUNK - 1) / SCAN_CHUNK);
    scan3_kernel<<<(NB + 255) / 256, 256, 0, stream>>>(bptr, cursor, bsums, NB, E);
    fill_kernel<<<(E + 255) / 256, 256, 0, stream>>>(src, dst, dinv, cursor, rec, E);

    const int gemmGrid = (N + 63) / 64;

    // --- layer 0 ---
    gemm_kernel<128, 64><<<gemmGrid, 256, 0, stream>>>(x, W0, B1, N);
    agg_kernel<64><<<NB, 256, 0, stream>>>(B1, bptr, rec, dinv, B2, N);

    // --- layer 1 ---
    gemm_kernel<64, 64><<<gemmGrid, 256, 0, stream>>>(B2, W1, B1, N);
    agg_kernel<64><<<NB, 256, 0, stream>>>(B1, bptr, rec, dinv, B2, N);

    // --- layer 2 ---
    gemm_kernel<64, 40><<<gemmGrid, 256, 0, stream>>>(B2, W2, B1, N);
    agg_kernel<40><<<NB, 256, 0, stream>>>(B1, bptr, rec, dinv, out, N);
}

// Round 6
// 583.399 us; speedup vs baseline: 3.1301x; 3.1301x over previous
//
#include <hip/hip_runtime.h>
#include <cstddef>

// ---------------------------------------------------------------------------
// GCN: out = relu(Â relu(Â relu(Â (x W0)) W1) W2),  Â = D^-1/2 (A+I) D^-1/2
// R6: per-node gather agg (quarter-wave float4, 8 rows in flight/wave) +
// two-phase CSR build (bucket fill -> per-bucket counting sort) to kill the
// fill write-amplification. No fp32 atomics anywhere.
// ---------------------------------------------------------------------------

constexpr int BK = 32;  // nodes per bucket (N = 100000 = 3125 * 32)

struct EdgeB  { unsigned int key; float norm; };  // bucket rec: (dstLocal<<27)|src
struct EdgeRec { int src; float norm; };          // per-node rec

__global__ void deg_kernel(const int* __restrict__ dst, int E, int* __restrict__ cnt) {
    int i = blockIdx.x * blockDim.x + threadIdx.x;
    if (i < E) atomicAdd(&cnt[dst[i]], 1);
}

__global__ void dinv_kernel(const int* __restrict__ cnt, float* __restrict__ dinv, int N) {
    int i = blockIdx.x * blockDim.x + threadIdx.x;
    if (i < N) dinv[i] = rsqrtf((float)cnt[i] + 1.0f);  // +1 self-loop; deg>0 always
}

__global__ void bucketsum_kernel(const int* __restrict__ cnt, int* __restrict__ bcnt,
                                 int nb, int N) {
    int b = blockIdx.x * blockDim.x + threadIdx.x;
    if (b < nb) {
        int s = 0, base = b * BK;
#pragma unroll
        for (int i = 0; i < BK; ++i) {
            int idx = base + i;
            s += (idx < N) ? cnt[idx] : 0;
        }
        bcnt[b] = s;
    }
}

// ---- exclusive scan (3-kernel, 4096 items/block) ----
constexpr int SCAN_ITEMS = 16;
constexpr int SCAN_CHUNK = 256 * SCAN_ITEMS;  // 4096

__global__ __launch_bounds__(256) void scan1_kernel(const int* __restrict__ in,
                                                    int* __restrict__ outp,
                                                    int* __restrict__ blockSums, int n) {
    __shared__ int sh[256];
    int tbase = blockIdx.x * SCAN_CHUNK + threadIdx.x * SCAN_ITEMS;
    int vals[SCAN_ITEMS];
    int tsum = 0;
#pragma unroll
    for (int j = 0; j < SCAN_ITEMS; ++j) {
        int idx = tbase + j;
        int v = (idx < n) ? in[idx] : 0;
        vals[j] = tsum;
        tsum += v;
    }
    sh[threadIdx.x] = tsum;
    __syncthreads();
    for (int off = 1; off < 256; off <<= 1) {
        int v = (threadIdx.x >= off) ? sh[threadIdx.x - off] : 0;
        __syncthreads();
        sh[threadIdx.x] += v;
        __syncthreads();
    }
    int texcl = sh[threadIdx.x] - tsum;
    if (threadIdx.x == 255) blockSums[blockIdx.x] = sh[255];
#pragma unroll
    for (int j = 0; j < SCAN_ITEMS; ++j) {
        int idx = tbase + j;
        if (idx < n) outp[idx] = texcl + vals[j];
    }
}

__global__ void scan2_kernel(int* __restrict__ blockSums, int nb) {
    if (threadIdx.x == 0 && blockIdx.x == 0) {
        int run = 0;
        for (int i = 0; i < nb; ++i) { int v = blockSums[i]; blockSums[i] = run; run += v; }
    }
}

// finalize scan; optionally mirror into cursor
__global__ __launch_bounds__(256) void scan3_kernel(int* __restrict__ ptr,
                                                    int* __restrict__ cursor,
                                                    const int* __restrict__ blockSums,
                                                    int n, int E, int withCursor) {
    int idx = blockIdx.x * blockDim.x + threadIdx.x;
    if (idx < n) {
        int r = ptr[idx] + blockSums[idx / SCAN_CHUNK];
        ptr[idx] = r;
        if (withCursor) cursor[idx] = r;
    }
    if (idx == 0) ptr[n] = E;
}

// scatter edges to bucket slots (3125 active write tails -> no write amp)
__global__ void fillb_kernel(const int* __restrict__ src, const int* __restrict__ dst,
                             const float* __restrict__ dinv, int* __restrict__ cursor,
                             EdgeB* __restrict__ recB, int E) {
    int e = blockIdx.x * blockDim.x + threadIdx.x;
    if (e < E) {
        int s = src[e], d = dst[e];
        int slot = atomicAdd(&cursor[d / BK], 1);
        EdgeB r;
        r.key  = ((unsigned)(d & (BK - 1)) << 27) | (unsigned)s;
        r.norm = dinv[s] * dinv[d];
        recB[slot] = r;
    }
}

// per-bucket counting sort into per-node CSR order (writes stay in the
// bucket's ~4KB rec region -> cache-line reuse within one block)
__global__ __launch_bounds__(256) void sort_kernel(const EdgeB* __restrict__ recB,
                                                   const int* __restrict__ bptr,
                                                   const int* __restrict__ rowptr,
                                                   EdgeRec* __restrict__ rec, int N) {
    __shared__ int curs[BK];
    const int b = blockIdx.x;
    const int base = b * BK;
    if (threadIdx.x < BK)
        curs[threadIdx.x] = (base + threadIdx.x < N) ? rowptr[base + threadIdx.x] : 0;
    __syncthreads();
    const int beg = bptr[b], end = bptr[b + 1];
    for (int i = beg + threadIdx.x; i < end; i += 256) {
        EdgeB r = recB[i];
        int slot = atomicAdd(&curs[r.key >> 27], 1);
        EdgeRec o;
        o.src  = (int)(r.key & 0x7FFFFFFu);
        o.norm = r.norm;
        rec[slot] = o;
    }
}

// ---------------------------------------------------------------------------
// Register-tiled GEMM: A[N,K] @ W[K,M] -> out[N,M].
// Block = 256 thr = 16x16 grid, 4x4 outputs/thread => 64 rows x 64 cols.
// ---------------------------------------------------------------------------
template <int K, int M>
__global__ __launch_bounds__(256) void gemm_kernel(const float* __restrict__ A,
                                                   const float* __restrict__ W,
                                                   float* __restrict__ out, int N) {
    constexpr int KC = 64;
    constexpr int SA = 68;
    __shared__ float Ws[K * M];
    __shared__ float As[KC * SA];   // As[k][row]
    for (int i = threadIdx.x; i < K * M; i += 256) Ws[i] = W[i];

    const int tr = threadIdx.x & 15;
    const int tc = threadIdx.x >> 4;
    const int r0 = tr * 4, c0 = tc * 4;
    const int row0 = blockIdx.x * 64;
    const bool colAct = (c0 < M);

    float acc[4][4] = {};

    for (int k0 = 0; k0 < K; k0 += KC) {
        __syncthreads();
        {
            const int kq = threadIdx.x & 15;
            const int rr = threadIdx.x >> 4;
#pragma unroll
            for (int p = 0; p < 4; ++p) {
                int row = rr + p * 16;
                int grow = row0 + row;
                float4 v = make_float4(0.f, 0.f, 0.f, 0.f);
                if (grow < N)
                    v = *reinterpret_cast<const float4*>(&A[(size_t)grow * K + k0 + kq * 4]);
                As[(kq * 4 + 0) * SA + row] = v.x;
                As[(kq * 4 + 1) * SA + row] = v.y;
                As[(kq * 4 + 2) * SA + row] = v.z;
                As[(kq * 4 + 3) * SA + row] = v.w;
            }
        }
        __syncthreads();
        if (colAct) {
#pragma unroll 8
            for (int kk = 0; kk < KC; ++kk) {
                float4 a = *reinterpret_cast<const float4*>(&As[kk * SA + r0]);
                float4 b = *reinterpret_cast<const float4*>(&Ws[(k0 + kk) * M + c0]);
                acc[0][0] = fmaf(a.x, b.x, acc[0][0]); acc[0][1] = fmaf(a.x, b.y, acc[0][1]);
                acc[0][2] = fmaf(a.x, b.z, acc[0][2]); acc[0][3] = fmaf(a.x, b.w, acc[0][3]);
                acc[1][0] = fmaf(a.y, b.x, acc[1][0]); acc[1][1] = fmaf(a.y, b.y, acc[1][1]);
                acc[1][2] = fmaf(a.y, b.z, acc[1][2]); acc[1][3] = fmaf(a.y, b.w, acc[1][3]);
                acc[2][0] = fmaf(a.z, b.x, acc[2][0]); acc[2][1] = fmaf(a.z, b.y, acc[2][1]);
                acc[2][2] = fmaf(a.z, b.z, acc[2][2]); acc[2][3] = fmaf(a.z, b.w, acc[2][3]);
                acc[3][0] = fmaf(a.w, b.x, acc[3][0]); acc[3][1] = fmaf(a.w, b.y, acc[3][1]);
                acc[3][2] = fmaf(a.w, b.z, acc[3][2]); acc[3][3] = fmaf(a.w, b.w, acc[3][3]);
            }
        }
    }

    if (colAct) {
#pragma unroll
        for (int i = 0; i < 4; ++i) {
            int grow = row0 + r0 + i;
            if (grow < N) {
                float4 o = make_float4(acc[i][0], acc[i][1], acc[i][2], acc[i][3]);
                *reinterpret_cast<float4*>(&out[(size_t)grow * M + c0]) = o;
            }
        }
    }
}

// ---------------------------------------------------------------------------
// Quarter-wave gather aggregation: one wave per node. Each 16-lane quarter
// handles a different edge (lane = float4 of 4 features -> 256B row/quarter),
// 2-deep unroll => 8 rows in flight per wave. shfl_xor(16,32) combine.
// Self-loop + ReLU fused.
// ---------------------------------------------------------------------------
template <int D>
__global__ __launch_bounds__(256) void agg_kernel(const float* __restrict__ t,
                                                  const int* __restrict__ rowptr,
                                                  const EdgeRec* __restrict__ rec,
                                                  const float* __restrict__ dinv,
                                                  float* __restrict__ out, int N) {
    int n = blockIdx.x * 4 + (threadIdx.x >> 6);
    if (n >= N) return;
    const int lane = threadIdx.x & 63;
    const int q  = lane >> 4;          // quarter 0..3
    const int fl = (lane & 15) * 4;    // feature base
    const bool act = (fl < D);
    const int beg = rowptr[n], end = rowptr[n + 1];

    float ax = 0.f, ay = 0.f, az = 0.f, aw = 0.f;
    if (q == 0 && act) {   // self-loop on quarter 0
        float di = dinv[n];
        float4 v = *reinterpret_cast<const float4*>(&t[(size_t)n * D + fl]);
        float s = di * di;
        ax = s * v.x; ay = s * v.y; az = s * v.z; aw = s * v.w;
    }

    int i = beg + q;   // quarter q owns indices == q (mod 4)
    for (; i + 4 < end; i += 8) {
        EdgeRec r0 = rec[i];
        EdgeRec r1 = rec[i + 4];
        if (act) {
            float4 v0 = *reinterpret_cast<const float4*>(&t[(size_t)r0.src * D + fl]);
            float4 v1 = *reinterpret_cast<const float4*>(&t[(size_t)r1.src * D + fl]);
            ax = fmaf(v0.x, r0.norm, ax); ay = fmaf(v0.y, r0.norm, ay);
            az = fmaf(v0.z, r0.norm, az); aw = fmaf(v0.w, r0.norm, aw);
            ax = fmaf(v1.x, r1.norm, ax); ay = fmaf(v1.y, r1.norm, ay);
            az = fmaf(v1.z, r1.norm, az); aw = fmaf(v1.w, r1.norm, aw);
        }
    }
    if (i < end) {
        EdgeRec r = rec[i];
        if (act) {
            float4 v = *reinterpret_cast<const float4*>(&t[(size_t)r.src * D + fl]);
            ax = fmaf(v.x, r.norm, ax); ay = fmaf(v.y, r.norm, ay);
            az = fmaf(v.z, r.norm, az); aw = fmaf(v.w, r.norm, aw);
        }
    }

    // combine quarters: lanes with same (lane&15) across q0..q3
    ax += __shfl_xor(ax, 16); ay += __shfl_xor(ay, 16);
    az += __shfl_xor(az, 16); aw += __shfl_xor(aw, 16);
    ax += __shfl_xor(ax, 32); ay += __shfl_xor(ay, 32);
    az += __shfl_xor(az, 32); aw += __shfl_xor(aw, 32);

    if (q == 0 && act) {
        float4 o = make_float4(fmaxf(ax, 0.f), fmaxf(ay, 0.f),
                               fmaxf(az, 0.f), fmaxf(aw, 0.f));
        *reinterpret_cast<float4*>(&out[(size_t)n * D + fl]) = o;
    }
}

extern "C" void kernel_launch(void* const* d_in, const int* in_sizes, int n_in,
                              void* d_out, int out_size, void* d_ws, size_t ws_size,
                              hipStream_t stream) {
    const float* x  = (const float*)d_in[0];
    const int*   ei = (const int*)d_in[1];   // [2, E] row-major, int32
    const float* W0 = (const float*)d_in[2]; // [128,64]
    const float* W1 = (const float*)d_in[3]; // [64,64]
    const float* W2 = (const float*)d_in[4]; // [64,40]
    float* out = (float*)d_out;

    const int N = in_sizes[0] / 128;
    const int E = in_sizes[1] / 2;
    const int* src = ei;
    const int* dst = ei + E;
    const int NB = (N + BK - 1) / BK;   // 3125

    char* w = (char*)d_ws;
    size_t off = 0;
    auto alloc = [&](size_t bytes) {
        void* p = w + off;
        off += bytes;
        off = (off + 255) & ~(size_t)255;
        return p;
    };
    int*     cnt    = (int*)alloc((size_t)N * 4);
    float*   dinv   = (float*)alloc((size_t)N * 4);
    int*     bcnt   = (int*)alloc((size_t)NB * 4);
    int*     bptr   = (int*)alloc((size_t)(NB + 1) * 4);
    int*     bcur   = (int*)alloc((size_t)NB * 4);
    int*     rowptr = (int*)alloc((size_t)(N + 1) * 4);
    int*     bsums  = (int*)alloc(4096);
    EdgeRec* rec    = (EdgeRec*)alloc((size_t)E * 8);   // per-node CSR (persists)
    float*   B2     = (float*)alloc((size_t)N * 64 * 4);
    // region X: bucket recB (dead after sort) aliased under B1
    float*   B1     = (float*)alloc((size_t)N * 64 * 4);
    EdgeB*   recB   = (EdgeB*)B1;

    // --- normalization + two-phase CSR build (reused by all 3 layers) ---
    hipMemsetAsync(cnt, 0, (size_t)N * 4, stream);
    deg_kernel<<<(E + 255) / 256, 256, 0, stream>>>(dst, E, cnt);
    dinv_kernel<<<(N + 255) / 256, 256, 0, stream>>>(cnt, dinv, N);
    bucketsum_kernel<<<(NB + 255) / 256, 256, 0, stream>>>(cnt, bcnt, NB, N);

    // per-node rowptr scan
    const int nChunksN = (N + SCAN_CHUNK - 1) / SCAN_CHUNK;
    scan1_kernel<<<nChunksN, 256, 0, stream>>>(cnt, rowptr, bsums, N);
    scan2_kernel<<<1, 64, 0, stream>>>(bsums, nChunksN);
    scan3_kernel<<<(N + 255) / 256, 256, 0, stream>>>(rowptr, rowptr, bsums, N, E, 0);

    // bucket bptr scan (+cursor)
    const int nChunksB = (NB + SCAN_CHUNK - 1) / SCAN_CHUNK;
    scan1_kernel<<<nChunksB, 256, 0, stream>>>(bcnt, bptr, bsums, NB);
    scan2_kernel<<<1, 64, 0, stream>>>(bsums, nChunksB);
    scan3_kernel<<<(NB + 255) / 256, 256, 0, stream>>>(bptr, bcur, bsums, NB, E, 1);

    fillb_kernel<<<(E + 255) / 256, 256, 0, stream>>>(src, dst, dinv, bcur, recB, E);
    sort_kernel<<<NB, 256, 0, stream>>>(recB, bptr, rowptr, rec, N);

    const int gemmGrid = (N + 63) / 64;

    // --- layer 0 ---
    gemm_kernel<128, 64><<<gemmGrid, 256, 0, stream>>>(x, W0, B1, N);
    agg_kernel<64><<<(N + 3) / 4, 256, 0, stream>>>(B1, rowptr, rec, dinv, B2, N);

    // --- layer 1 ---
    gemm_kernel<64, 64><<<gemmGrid, 256, 0, stream>>>(B2, W1, B1, N);
    agg_kernel<64><<<(N + 3) / 4, 256, 0, stream>>>(B1, rowptr, rec, dinv, B2, N);

    // --- layer 2 ---
    gemm_kernel<64, 40><<<gemmGrid, 256, 0, stream>>>(B2, W2, B1, N);
    agg_kernel<40><<<(N + 3) / 4, 256, 0, stream>>>(B1, rowptr, rec, dinv, out, N);
}

// Round 7
// 464.101 us; speedup vs baseline: 3.9347x; 1.2571x over previous
//
#include <hip/hip_runtime.h>
#include <cstddef>

// ---------------------------------------------------------------------------
// GCN: out = relu(Â relu(Â relu(Â (x W0)) W1) W2),  Â = D^-1/2 (A+I) D^-1/2
// R7: CSR build via histogram + scan + deterministic scatter (counting sort,
// zero global atomics in the scatter path) -> no write amplification, no
// cursor-line ping-pong. Agg = per-node quarter-wave float4 gather (proven).
// ---------------------------------------------------------------------------

constexpr int NBLK  = 512;   // blocks for pass A / pass B (mapping must match)
constexpr int NPMAX = 512;   // max partitions (256 nodes each)

struct EdgeB  { unsigned int key; float norm; };  // key = (dstLocal<<17) | src
struct EdgeRec { int src; float norm; };          // per-node CSR record

__global__ void dinv_kernel(const int* __restrict__ cnt, float* __restrict__ dinv, int N) {
    int i = blockIdx.x * blockDim.x + threadIdx.x;
    if (i < N) dinv[i] = rsqrtf((float)cnt[i] + 1.0f);  // +1 self-loop; deg>0 always
}

// Pass A: per-block partition histogram (LDS) + fused per-node degree count.
__global__ __launch_bounds__(256) void passA_kernel(const int* __restrict__ dst, int E,
                                                    int* __restrict__ cnt,
                                                    int* __restrict__ histG, int NP) {
    __shared__ int hist[NPMAX];
    for (int i = threadIdx.x; i < NP; i += 256) hist[i] = 0;
    __syncthreads();
    for (int e = blockIdx.x * 256 + threadIdx.x; e < E; e += NBLK * 256) {
        int d = dst[e];
        atomicAdd(&cnt[d], 1);          // global per-node degree (spread, 100K addrs)
        atomicAdd(&hist[d >> 8], 1);    // LDS partition histogram
    }
    __syncthreads();
    for (int p = threadIdx.x; p < NP; p += 256)
        histG[p * NBLK + blockIdx.x] = hist[p];   // p-major, block-minor
}

// ---- exclusive scan (3-kernel, 4096 items/block) ----
constexpr int SCAN_ITEMS = 16;
constexpr int SCAN_CHUNK = 256 * SCAN_ITEMS;  // 4096

__global__ __launch_bounds__(256) void scan1_kernel(const int* __restrict__ in,
                                                    int* __restrict__ outp,
                                                    int* __restrict__ blockSums, int n) {
    __shared__ int sh[256];
    int tbase = blockIdx.x * SCAN_CHUNK + threadIdx.x * SCAN_ITEMS;
    int vals[SCAN_ITEMS];
    int tsum = 0;
#pragma unroll
    for (int j = 0; j < SCAN_ITEMS; ++j) {
        int idx = tbase + j;
        int v = (idx < n) ? in[idx] : 0;
        vals[j] = tsum;
        tsum += v;
    }
    sh[threadIdx.x] = tsum;
    __syncthreads();
    for (int off = 1; off < 256; off <<= 1) {
        int v = (threadIdx.x >= off) ? sh[threadIdx.x - off] : 0;
        __syncthreads();
        sh[threadIdx.x] += v;
        __syncthreads();
    }
    int texcl = sh[threadIdx.x] - tsum;
    if (threadIdx.x == 255) blockSums[blockIdx.x] = sh[255];
#pragma unroll
    for (int j = 0; j < SCAN_ITEMS; ++j) {
        int idx = tbase + j;
        if (idx < n) outp[idx] = texcl + vals[j];
    }
}

__global__ void scan2_kernel(int* __restrict__ blockSums, int nb) {
    if (threadIdx.x == 0 && blockIdx.x == 0) {
        int run = 0;
        for (int i = 0; i < nb; ++i) { int v = blockSums[i]; blockSums[i] = run; run += v; }
    }
}

__global__ __launch_bounds__(256) void scan3_kernel(int* __restrict__ ptr,
                                                    const int* __restrict__ blockSums,
                                                    int n, int E) {
    int idx = blockIdx.x * blockDim.x + threadIdx.x;
    if (idx < n) ptr[idx] += blockSums[idx / SCAN_CHUNK];
    if (idx == 0) ptr[n] = E;   // sentinel
}

// Pass B: deterministic scatter to partition-sorted order. LDS cursors only.
__global__ __launch_bounds__(256) void passB_kernel(const int* __restrict__ src,
                                                    const int* __restrict__ dst,
                                                    const float* __restrict__ dinv,
                                                    const int* __restrict__ histS,
                                                    EdgeB* __restrict__ recP,
                                                    int E, int NP) {
    __shared__ int cur[NPMAX];
    for (int i = threadIdx.x; i < NP; i += 256) cur[i] = histS[i * NBLK + blockIdx.x];
    __syncthreads();
    for (int e = blockIdx.x * 256 + threadIdx.x; e < E; e += NBLK * 256) {
        int s = src[e], d = dst[e];
        int slot = atomicAdd(&cur[d >> 8], 1);   // LDS atomic, block-private run
        EdgeB r;
        r.key  = ((unsigned)(d & 255) << 17) | (unsigned)s;
        r.norm = dinv[s] * dinv[d];
        recP[slot] = r;
    }
}

// Pass C: one block per partition. Local per-node count -> LDS scan ->
// write rowptr slice -> scatter into per-node CSR order (block-local region).
__global__ __launch_bounds__(256) void passC_kernel(const EdgeB* __restrict__ recP,
                                                    const int* __restrict__ histS,
                                                    EdgeRec* __restrict__ rec,
                                                    int* __restrict__ rowptr,
                                                    int N, int E) {
    __shared__ int cntL[256];
    __shared__ int sh[256];
    const int p = blockIdx.x;
    const int S    = histS[p * NBLK];
    const int Eend = histS[(p + 1) * NBLK];   // sentinel covers last partition
    cntL[threadIdx.x] = 0;
    __syncthreads();
    for (int i = S + threadIdx.x; i < Eend; i += 256)
        atomicAdd(&cntL[recP[i].key >> 17], 1);
    __syncthreads();
    int v = cntL[threadIdx.x];
    sh[threadIdx.x] = v;
    __syncthreads();
    for (int off = 1; off < 256; off <<= 1) {
        int u = (threadIdx.x >= off) ? sh[threadIdx.x - off] : 0;
        __syncthreads();
        sh[threadIdx.x] += u;
        __syncthreads();
    }
    int excl = sh[threadIdx.x] - v;          // exclusive within partition
    int node = p * 256 + threadIdx.x;
    if (node < N) rowptr[node] = S + excl;
    if (p == 0 && threadIdx.x == 0) rowptr[N] = E;
    __syncthreads();
    cntL[threadIdx.x] = S + excl;            // reuse as cursor
    __syncthreads();
    for (int i = S + threadIdx.x; i < Eend; i += 256) {
        EdgeB r = recP[i];
        int slot = atomicAdd(&cntL[r.key >> 17], 1);
        EdgeRec o;
        o.src  = (int)(r.key & 0x1FFFFu);
        o.norm = r.norm;
        rec[slot] = o;
    }
}

// ---------------------------------------------------------------------------
// Register-tiled GEMM: A[N,K] @ W[K,M] -> out[N,M].
// Block = 256 thr = 16x16 grid, 4x4 outputs/thread => 64 rows x 64 cols.
// ---------------------------------------------------------------------------
template <int K, int M>
__global__ __launch_bounds__(256) void gemm_kernel(const float* __restrict__ A,
                                                   const float* __restrict__ W,
                                                   float* __restrict__ out, int N) {
    constexpr int KC = 64;
    constexpr int SA = 68;
    __shared__ float Ws[K * M];
    __shared__ float As[KC * SA];   // As[k][row]
    for (int i = threadIdx.x; i < K * M; i += 256) Ws[i] = W[i];

    const int tr = threadIdx.x & 15;
    const int tc = threadIdx.x >> 4;
    const int r0 = tr * 4, c0 = tc * 4;
    const int row0 = blockIdx.x * 64;
    const bool colAct = (c0 < M);

    float acc[4][4] = {};

    for (int k0 = 0; k0 < K; k0 += KC) {
        __syncthreads();
        {
            const int kq = threadIdx.x & 15;
            const int rr = threadIdx.x >> 4;
#pragma unroll
            for (int p = 0; p < 4; ++p) {
                int row = rr + p * 16;
                int grow = row0 + row;
                float4 v = make_float4(0.f, 0.f, 0.f, 0.f);
                if (grow < N)
                    v = *reinterpret_cast<const float4*>(&A[(size_t)grow * K + k0 + kq * 4]);
                As[(kq * 4 + 0) * SA + row] = v.x;
                As[(kq * 4 + 1) * SA + row] = v.y;
                As[(kq * 4 + 2) * SA + row] = v.z;
                As[(kq * 4 + 3) * SA + row] = v.w;
            }
        }
        __syncthreads();
        if (colAct) {
#pragma unroll 8
            for (int kk = 0; kk < KC; ++kk) {
                float4 a = *reinterpret_cast<const float4*>(&As[kk * SA + r0]);
                float4 b = *reinterpret_cast<const float4*>(&Ws[(k0 + kk) * M + c0]);
                acc[0][0] = fmaf(a.x, b.x, acc[0][0]); acc[0][1] = fmaf(a.x, b.y, acc[0][1]);
                acc[0][2] = fmaf(a.x, b.z, acc[0][2]); acc[0][3] = fmaf(a.x, b.w, acc[0][3]);
                acc[1][0] = fmaf(a.y, b.x, acc[1][0]); acc[1][1] = fmaf(a.y, b.y, acc[1][1]);
                acc[1][2] = fmaf(a.y, b.z, acc[1][2]); acc[1][3] = fmaf(a.y, b.w, acc[1][3]);
                acc[2][0] = fmaf(a.z, b.x, acc[2][0]); acc[2][1] = fmaf(a.z, b.y, acc[2][1]);
                acc[2][2] = fmaf(a.z, b.z, acc[2][2]); acc[2][3] = fmaf(a.z, b.w, acc[2][3]);
                acc[3][0] = fmaf(a.w, b.x, acc[3][0]); acc[3][1] = fmaf(a.w, b.y, acc[3][1]);
                acc[3][2] = fmaf(a.w, b.z, acc[3][2]); acc[3][3] = fmaf(a.w, b.w, acc[3][3]);
            }
        }
    }

    if (colAct) {
#pragma unroll
        for (int i = 0; i < 4; ++i) {
            int grow = row0 + r0 + i;
            if (grow < N) {
                float4 o = make_float4(acc[i][0], acc[i][1], acc[i][2], acc[i][3]);
                *reinterpret_cast<float4*>(&out[(size_t)grow * M + c0]) = o;
            }
        }
    }
}

// ---------------------------------------------------------------------------
// Quarter-wave gather aggregation: one wave per node. Each 16-lane quarter
// handles a different edge (lane = float4 of 4 features -> 256B row/quarter),
// 2-deep unroll => 8 rows in flight per wave. shfl_xor(16,32) combine.
// Self-loop + ReLU fused.
// ---------------------------------------------------------------------------
template <int D>
__global__ __launch_bounds__(256) void agg_kernel(const float* __restrict__ t,
                                                  const int* __restrict__ rowptr,
                                                  const EdgeRec* __restrict__ rec,
                                                  const float* __restrict__ dinv,
                                                  float* __restrict__ out, int N) {
    int n = blockIdx.x * 4 + (threadIdx.x >> 6);
    if (n >= N) return;
    const int lane = threadIdx.x & 63;
    const int q  = lane >> 4;          // quarter 0..3
    const int fl = (lane & 15) * 4;    // feature base
    const bool act = (fl < D);
    const int beg = rowptr[n], end = rowptr[n + 1];

    float ax = 0.f, ay = 0.f, az = 0.f, aw = 0.f;
    if (q == 0 && act) {   // self-loop on quarter 0
        float di = dinv[n];
        float4 v = *reinterpret_cast<const float4*>(&t[(size_t)n * D + fl]);
        float s = di * di;
        ax = s * v.x; ay = s * v.y; az = s * v.z; aw = s * v.w;
    }

    int i = beg + q;   // quarter q owns indices == q (mod 4)
    for (; i + 4 < end; i += 8) {
        EdgeRec r0 = rec[i];
        EdgeRec r1 = rec[i + 4];
        if (act) {
            float4 v0 = *reinterpret_cast<const float4*>(&t[(size_t)r0.src * D + fl]);
            float4 v1 = *reinterpret_cast<const float4*>(&t[(size_t)r1.src * D + fl]);
            ax = fmaf(v0.x, r0.norm, ax); ay = fmaf(v0.y, r0.norm, ay);
            az = fmaf(v0.z, r0.norm, az); aw = fmaf(v0.w, r0.norm, aw);
            ax = fmaf(v1.x, r1.norm, ax); ay = fmaf(v1.y, r1.norm, ay);
            az = fmaf(v1.z, r1.norm, az); aw = fmaf(v1.w, r1.norm, aw);
        }
    }
    if (i < end) {
        EdgeRec r = rec[i];
        if (act) {
            float4 v = *reinterpret_cast<const float4*>(&t[(size_t)r.src * D + fl]);
            ax = fmaf(v.x, r.norm, ax); ay = fmaf(v.y, r.norm, ay);
            az = fmaf(v.z, r.norm, az); aw = fmaf(v.w, r.norm, aw);
        }
    }

    ax += __shfl_xor(ax, 16); ay += __shfl_xor(ay, 16);
    az += __shfl_xor(az, 16); aw += __shfl_xor(aw, 16);
    ax += __shfl_xor(ax, 32); ay += __shfl_xor(ay, 32);
    az += __shfl_xor(az, 32); aw += __shfl_xor(aw, 32);

    if (q == 0 && act) {
        float4 o = make_float4(fmaxf(ax, 0.f), fmaxf(ay, 0.f),
                               fmaxf(az, 0.f), fmaxf(aw, 0.f));
        *reinterpret_cast<float4*>(&out[(size_t)n * D + fl]) = o;
    }
}

extern "C" void kernel_launch(void* const* d_in, const int* in_sizes, int n_in,
                              void* d_out, int out_size, void* d_ws, size_t ws_size,
                              hipStream_t stream) {
    const float* x  = (const float*)d_in[0];
    const int*   ei = (const int*)d_in[1];   // [2, E] row-major, int32
    const float* W0 = (const float*)d_in[2]; // [128,64]
    const float* W1 = (const float*)d_in[3]; // [64,64]
    const float* W2 = (const float*)d_in[4]; // [64,40]
    float* out = (float*)d_out;

    const int N = in_sizes[0] / 128;
    const int E = in_sizes[1] / 2;
    const int* src = ei;
    const int* dst = ei + E;
    const int NP = (N + 255) / 256;          // 391 partitions of 256 nodes
    const int histItems = NP * NBLK;         // 200192

    char* w = (char*)d_ws;
    size_t off = 0;
    auto alloc = [&](size_t bytes) {
        void* p = w + off;
        off += bytes;
        off = (off + 255) & ~(size_t)255;
        return p;
    };
    int*     cnt    = (int*)alloc((size_t)N * 4);
    float*   dinv   = (float*)alloc((size_t)N * 4);
    int*     histG  = (int*)alloc((size_t)histItems * 4);
    int*     histS  = (int*)alloc((size_t)(histItems + 1) * 4);
    int*     rowptr = (int*)alloc((size_t)(N + 1) * 4);
    int*     bsums  = (int*)alloc(4096);
    EdgeRec* rec    = (EdgeRec*)alloc((size_t)E * 8);   // per-node CSR (persists)
    float*   B2     = (float*)alloc((size_t)N * 64 * 4);
    float*   B1     = (float*)alloc((size_t)N * 64 * 4);
    EdgeB*   recP   = (EdgeB*)B1;   // partition-sorted recs, dead after passC

    // --- normalization + CSR build (counting sort; reused by all 3 layers) ---
    hipMemsetAsync(cnt, 0, (size_t)N * 4, stream);
    passA_kernel<<<NBLK, 256, 0, stream>>>(dst, E, cnt, histG, NP);
    dinv_kernel<<<(N + 255) / 256, 256, 0, stream>>>(cnt, dinv, N);
    const int nCh = (histItems + SCAN_CHUNK - 1) / SCAN_CHUNK;
    scan1_kernel<<<nCh, 256, 0, stream>>>(histG, histS, bsums, histItems);
    scan2_kernel<<<1, 64, 0, stream>>>(bsums, nCh);
    scan3_kernel<<<(histItems + 255) / 256, 256, 0, stream>>>(histS, bsums, histItems, E);
    passB_kernel<<<NBLK, 256, 0, stream>>>(src, dst, dinv, histS, recP, E, NP);
    passC_kernel<<<NP, 256, 0, stream>>>(recP, histS, rec, rowptr, N, E);

    const int gemmGrid = (N + 63) / 64;

    // --- layer 0 ---
    gemm_kernel<128, 64><<<gemmGrid, 256, 0, stream>>>(x, W0, B1, N);
    agg_kernel<64><<<(N + 3) / 4, 256, 0, stream>>>(B1, rowptr, rec, dinv, B2, N);

    // --- layer 1 ---
    gemm_kernel<64, 64><<<gemmGrid, 256, 0, stream>>>(B2, W1, B1, N);
    agg_kernel<64><<<(N + 3) / 4, 256, 0, stream>>>(B1, rowptr, rec, dinv, B2, N);

    // --- layer 2 ---
    gemm_kernel<64, 40><<<gemmGrid, 256, 0, stream>>>(B2, W2, B1, N);
    agg_kernel<40><<<(N + 3) / 4, 256, 0, stream>>>(B1, rowptr, rec, dinv, out, N);
}

// Round 8
// 396.661 us; speedup vs baseline: 4.6037x; 1.1700x over previous
//
#include <hip/hip_runtime.h>
#include <cstddef>

// ---------------------------------------------------------------------------
// GCN: out = relu(Â relu(Â relu(Â (x W0)) W1) W2),  Â = D^-1/2 (A+I) D^-1/2
// R8: factor the norm out of the edge loop:  Â h = D^-1/2 (A+I) (D^-1/2 h).
// GEMM epilogue scales rows by dinv; agg is a pure row-sum gather; finalize
// multiplies by dinv[n]. Edge records are 4B (src only). CSR build is a
// counting sort with ZERO global atomics (degrees counted in passC).
// ---------------------------------------------------------------------------

constexpr int NBLK  = 512;   // blocks for pass A / pass B (mapping must match)
constexpr int NPMAX = 512;   // max partitions (256 nodes each)

// Pass A: per-block partition histogram (LDS only).
__global__ __launch_bounds__(256) void passA_kernel(const int* __restrict__ dst, int E,
                                                    int* __restrict__ histG, int NP) {
    __shared__ int hist[NPMAX];
    for (int i = threadIdx.x; i < NP; i += 256) hist[i] = 0;
    __syncthreads();
    for (int e = blockIdx.x * 256 + threadIdx.x; e < E; e += NBLK * 256)
        atomicAdd(&hist[dst[e] >> 8], 1);
    __syncthreads();
    for (int p = threadIdx.x; p < NP; p += 256)
        histG[p * NBLK + blockIdx.x] = hist[p];   // p-major, block-minor
}

// ---- exclusive scan (3-kernel, 4096 items/block) ----
constexpr int SCAN_ITEMS = 16;
constexpr int SCAN_CHUNK = 256 * SCAN_ITEMS;  // 4096

__global__ __launch_bounds__(256) void scan1_kernel(const int* __restrict__ in,
                                                    int* __restrict__ outp,
                                                    int* __restrict__ blockSums, int n) {
    __shared__ int sh[256];
    int tbase = blockIdx.x * SCAN_CHUNK + threadIdx.x * SCAN_ITEMS;
    int vals[SCAN_ITEMS];
    int tsum = 0;
#pragma unroll
    for (int j = 0; j < SCAN_ITEMS; ++j) {
        int idx = tbase + j;
        int v = (idx < n) ? in[idx] : 0;
        vals[j] = tsum;
        tsum += v;
    }
    sh[threadIdx.x] = tsum;
    __syncthreads();
    for (int off = 1; off < 256; off <<= 1) {
        int v = (threadIdx.x >= off) ? sh[threadIdx.x - off] : 0;
        __syncthreads();
        sh[threadIdx.x] += v;
        __syncthreads();
    }
    int texcl = sh[threadIdx.x] - tsum;
    if (threadIdx.x == 255) blockSums[blockIdx.x] = sh[255];
#pragma unroll
    for (int j = 0; j < SCAN_ITEMS; ++j) {
        int idx = tbase + j;
        if (idx < n) outp[idx] = texcl + vals[j];
    }
}

__global__ void scan2_kernel(int* __restrict__ blockSums, int nb) {
    if (threadIdx.x == 0 && blockIdx.x == 0) {
        int run = 0;
        for (int i = 0; i < nb; ++i) { int v = blockSums[i]; blockSums[i] = run; run += v; }
    }
}

__global__ __launch_bounds__(256) void scan3_kernel(int* __restrict__ ptr,
                                                    const int* __restrict__ blockSums,
                                                    int n, int E) {
    int idx = blockIdx.x * blockDim.x + threadIdx.x;
    if (idx < n) ptr[idx] += blockSums[idx / SCAN_CHUNK];
    if (idx == 0) ptr[n] = E;   // sentinel
}

// Pass B: deterministic scatter to partition-sorted order. LDS cursors only.
// Record = (dstLocal<<17) | src  (src < 2^17, dstLocal < 256) -> 4 bytes.
__global__ __launch_bounds__(256) void passB_kernel(const int* __restrict__ src,
                                                    const int* __restrict__ dst,
                                                    const int* __restrict__ histS,
                                                    unsigned* __restrict__ recP,
                                                    int E, int NP) {
    __shared__ int cur[NPMAX];
    for (int i = threadIdx.x; i < NP; i += 256) cur[i] = histS[i * NBLK + blockIdx.x];
    __syncthreads();
    for (int e = blockIdx.x * 256 + threadIdx.x; e < E; e += NBLK * 256) {
        int s = src[e], d = dst[e];
        int slot = atomicAdd(&cur[d >> 8], 1);   // LDS atomic, block-private run
        recP[slot] = ((unsigned)(d & 255) << 17) | (unsigned)s;
    }
}

// Pass C: one block per partition. Per-node degree count (LDS) -> dinv ->
// LDS scan -> rowptr slice -> scatter src into per-node CSR order.
__global__ __launch_bounds__(256) void passC_kernel(const unsigned* __restrict__ recP,
                                                    const int* __restrict__ histS,
                                                    int* __restrict__ rec,
                                                    int* __restrict__ rowptr,
                                                    float* __restrict__ dinv,
                                                    int N, int E) {
    __shared__ int cntL[256];
    __shared__ int sh[256];
    const int p = blockIdx.x;
    const int S    = histS[p * NBLK];
    const int Eend = histS[(p + 1) * NBLK];   // sentinel covers last partition
    cntL[threadIdx.x] = 0;
    __syncthreads();
    for (int i = S + threadIdx.x; i < Eend; i += 256)
        atomicAdd(&cntL[recP[i] >> 17], 1);
    __syncthreads();
    int v = cntL[threadIdx.x];                // this node's degree
    int node = p * 256 + threadIdx.x;
    if (node < N) dinv[node] = rsqrtf((float)v + 1.0f);  // +1 self-loop
    sh[threadIdx.x] = v;
    __syncthreads();
    for (int off = 1; off < 256; off <<= 1) {
        int u = (threadIdx.x >= off) ? sh[threadIdx.x - off] : 0;
        __syncthreads();
        sh[threadIdx.x] += u;
        __syncthreads();
    }
    int excl = sh[threadIdx.x] - v;           // exclusive within partition
    if (node < N) rowptr[node] = S + excl;
    if (p == 0 && threadIdx.x == 0) rowptr[N] = E;
    __syncthreads();
    cntL[threadIdx.x] = S + excl;             // reuse as cursor
    __syncthreads();
    for (int i = S + threadIdx.x; i < Eend; i += 256) {
        unsigned r = recP[i];
        int slot = atomicAdd(&cntL[r >> 17], 1);
        rec[slot] = (int)(r & 0x1FFFFu);
    }
}

// ---------------------------------------------------------------------------
// Register-tiled GEMM with fused row scale: out[row] = (A[row] @ W) * dinv[row].
// Block = 256 thr = 16x16 grid, 4x4 outputs/thread => 64 rows x 64 cols.
// ---------------------------------------------------------------------------
template <int K, int M>
__global__ __launch_bounds__(256) void gemm_kernel(const float* __restrict__ A,
                                                   const float* __restrict__ W,
                                                   const float* __restrict__ dinv,
                                                   float* __restrict__ out, int N) {
    constexpr int KC = 64;
    constexpr int SA = 68;
    __shared__ float Ws[K * M];
    __shared__ float As[KC * SA];   // As[k][row]
    for (int i = threadIdx.x; i < K * M; i += 256) Ws[i] = W[i];

    const int tr = threadIdx.x & 15;
    const int tc = threadIdx.x >> 4;
    const int r0 = tr * 4, c0 = tc * 4;
    const int row0 = blockIdx.x * 64;
    const bool colAct = (c0 < M);

    float acc[4][4] = {};

    for (int k0 = 0; k0 < K; k0 += KC) {
        __syncthreads();
        {
            const int kq = threadIdx.x & 15;
            const int rr = threadIdx.x >> 4;
#pragma unroll
            for (int p = 0; p < 4; ++p) {
                int row = rr + p * 16;
                int grow = row0 + row;
                float4 v = make_float4(0.f, 0.f, 0.f, 0.f);
                if (grow < N)
                    v = *reinterpret_cast<const float4*>(&A[(size_t)grow * K + k0 + kq * 4]);
                As[(kq * 4 + 0) * SA + row] = v.x;
                As[(kq * 4 + 1) * SA + row] = v.y;
                As[(kq * 4 + 2) * SA + row] = v.z;
                As[(kq * 4 + 3) * SA + row] = v.w;
            }
        }
        __syncthreads();
        if (colAct) {
#pragma unroll 8
            for (int kk = 0; kk < KC; ++kk) {
                float4 a = *reinterpret_cast<const float4*>(&As[kk * SA + r0]);
                float4 b = *reinterpret_cast<const float4*>(&Ws[(k0 + kk) * M + c0]);
                acc[0][0] = fmaf(a.x, b.x, acc[0][0]); acc[0][1] = fmaf(a.x, b.y, acc[0][1]);
                acc[0][2] = fmaf(a.x, b.z, acc[0][2]); acc[0][3] = fmaf(a.x, b.w, acc[0][3]);
                acc[1][0] = fmaf(a.y, b.x, acc[1][0]); acc[1][1] = fmaf(a.y, b.y, acc[1][1]);
                acc[1][2] = fmaf(a.y, b.z, acc[1][2]); acc[1][3] = fmaf(a.y, b.w, acc[1][3]);
                acc[2][0] = fmaf(a.z, b.x, acc[2][0]); acc[2][1] = fmaf(a.z, b.y, acc[2][1]);
                acc[2][2] = fmaf(a.z, b.z, acc[2][2]); acc[2][3] = fmaf(a.z, b.w, acc[2][3]);
                acc[3][0] = fmaf(a.w, b.x, acc[3][0]); acc[3][1] = fmaf(a.w, b.y, acc[3][1]);
                acc[3][2] = fmaf(a.w, b.z, acc[3][2]); acc[3][3] = fmaf(a.w, b.w, acc[3][3]);
            }
        }
    }

    if (colAct) {
#pragma unroll
        for (int i = 0; i < 4; ++i) {
            int grow = row0 + r0 + i;
            if (grow < N) {
                float s = dinv[grow];
                float4 o = make_float4(acc[i][0] * s, acc[i][1] * s,
                                       acc[i][2] * s, acc[i][3] * s);
                *reinterpret_cast<float4*>(&out[(size_t)grow * M + c0]) = o;
            }
        }
    }
}

// ---------------------------------------------------------------------------
// Quarter-wave gather aggregation (pure row-sum): one wave per node.
// Each 16-lane quarter handles a different edge (lane = float4 of 4 features
// -> 256B row/quarter), 2-deep unroll => 8 rows in flight per wave.
// out[n] = relu( dinv[n] * ( sum_e t'[src_e] + t'[n] ) )
// ---------------------------------------------------------------------------
template <int D>
__global__ __launch_bounds__(256) void agg_kernel(const float* __restrict__ t,
                                                  const int* __restrict__ rowptr,
                                                  const int* __restrict__ rec,
                                                  const float* __restrict__ dinv,
                                                  float* __restrict__ out, int N) {
    int n = blockIdx.x * 4 + (threadIdx.x >> 6);
    if (n >= N) return;
    const int lane = threadIdx.x & 63;
    const int q  = lane >> 4;          // quarter 0..3
    const int fl = (lane & 15) * 4;    // feature base
    const bool act = (fl < D);
    const int beg = rowptr[n], end = rowptr[n + 1];

    float ax = 0.f, ay = 0.f, az = 0.f, aw = 0.f;
    if (q == 0 && act) {   // self-loop: t'[n]
        float4 v = *reinterpret_cast<const float4*>(&t[(size_t)n * D + fl]);
        ax = v.x; ay = v.y; az = v.z; aw = v.w;
    }

    int i = beg + q;   // quarter q owns indices == q (mod 4)
    for (; i + 4 < end; i += 8) {
        int s0 = rec[i];
        int s1 = rec[i + 4];
        if (act) {
            float4 v0 = *reinterpret_cast<const float4*>(&t[(size_t)s0 * D + fl]);
            float4 v1 = *reinterpret_cast<const float4*>(&t[(size_t)s1 * D + fl]);
            ax += v0.x; ay += v0.y; az += v0.z; aw += v0.w;
            ax += v1.x; ay += v1.y; az += v1.z; aw += v1.w;
        }
    }
    if (i < end) {
        int s = rec[i];
        if (act) {
            float4 v = *reinterpret_cast<const float4*>(&t[(size_t)s * D + fl]);
            ax += v.x; ay += v.y; az += v.z; aw += v.w;
        }
    }

    ax += __shfl_xor(ax, 16); ay += __shfl_xor(ay, 16);
    az += __shfl_xor(az, 16); aw += __shfl_xor(aw, 16);
    ax += __shfl_xor(ax, 32); ay += __shfl_xor(ay, 32);
    az += __shfl_xor(az, 32); aw += __shfl_xor(aw, 32);

    if (q == 0 && act) {
        float di = dinv[n];
        float4 o = make_float4(fmaxf(di * ax, 0.f), fmaxf(di * ay, 0.f),
                               fmaxf(di * az, 0.f), fmaxf(di * aw, 0.f));
        *reinterpret_cast<float4*>(&out[(size_t)n * D + fl]) = o;
    }
}

extern "C" void kernel_launch(void* const* d_in, const int* in_sizes, int n_in,
                              void* d_out, int out_size, void* d_ws, size_t ws_size,
                              hipStream_t stream) {
    const float* x  = (const float*)d_in[0];
    const int*   ei = (const int*)d_in[1];   // [2, E] row-major, int32
    const float* W0 = (const float*)d_in[2]; // [128,64]
    const float* W1 = (const float*)d_in[3]; // [64,64]
    const float* W2 = (const float*)d_in[4]; // [64,40]
    float* out = (float*)d_out;

    const int N = in_sizes[0] / 128;
    const int E = in_sizes[1] / 2;
    const int* src = ei;
    const int* dst = ei + E;
    const int NP = (N + 255) / 256;          // 391 partitions of 256 nodes
    const int histItems = NP * NBLK;         // 200192

    char* w = (char*)d_ws;
    size_t off = 0;
    auto alloc = [&](size_t bytes) {
        void* p = w + off;
        off += bytes;
        off = (off + 255) & ~(size_t)255;
        return p;
    };
    float*    dinv   = (float*)alloc((size_t)N * 4);
    int*      histG  = (int*)alloc((size_t)histItems * 4);
    int*      histS  = (int*)alloc((size_t)(histItems + 1) * 4);
    int*      rowptr = (int*)alloc((size_t)(N + 1) * 4);
    int*      bsums  = (int*)alloc(4096);
    int*      rec    = (int*)alloc((size_t)E * 4);     // per-node CSR (persists)
    float*    B2     = (float*)alloc((size_t)N * 64 * 4);
    float*    B1     = (float*)alloc((size_t)N * 64 * 4);
    unsigned* recP   = (unsigned*)B1;   // partition-sorted recs, dead after passC

    // --- CSR build (counting sort, zero global atomics; reused by 3 layers) ---
    passA_kernel<<<NBLK, 256, 0, stream>>>(dst, E, histG, NP);
    const int nCh = (histItems + SCAN_CHUNK - 1) / SCAN_CHUNK;
    scan1_kernel<<<nCh, 256, 0, stream>>>(histG, histS, bsums, histItems);
    scan2_kernel<<<1, 64, 0, stream>>>(bsums, nCh);
    scan3_kernel<<<(histItems + 255) / 256, 256, 0, stream>>>(histS, bsums, histItems, E);
    passB_kernel<<<NBLK, 256, 0, stream>>>(src, dst, histS, recP, E, NP);
    passC_kernel<<<NP, 256, 0, stream>>>(recP, histS, rec, rowptr, dinv, N, E);

    const int gemmGrid = (N + 63) / 64;

    // --- layer 0 ---
    gemm_kernel<128, 64><<<gemmGrid, 256, 0, stream>>>(x, W0, dinv, B1, N);
    agg_kernel<64><<<(N + 3) / 4, 256, 0, stream>>>(B1, rowptr, rec, dinv, B2, N);

    // --- layer 1 ---
    gemm_kernel<64, 64><<<gemmGrid, 256, 0, stream>>>(B2, W1, dinv, B1, N);
    agg_kernel<64><<<(N + 3) / 4, 256, 0, stream>>>(B1, rowptr, rec, dinv, B2, N);

    // --- layer 2 ---
    gemm_kernel<64, 40><<<gemmGrid, 256, 0, stream>>>(B2, W2, dinv, B1, N);
    agg_kernel<40><<<(N + 3) / 4, 256, 0, stream>>>(B1, rowptr, rec, dinv, out, N);
}

// Round 10
// 390.028 us; speedup vs baseline: 4.6820x; 1.0170x over previous
//
#include <hip/hip_runtime.h>
#include <cstddef>

// ---------------------------------------------------------------------------
// GCN: out = relu(Â relu(Â relu(Â (x W0)) W1) W2),  Â = D^-1/2 (A+I) D^-1/2
// R10: R9's shfl-sourced agg fixed for wave convergence (uniform group count,
// clamped+predicated tail). Norm factored out of edge loop (R8); CSR via
// atomic-free counting sort (R7). Zero global atomics anywhere.
// ---------------------------------------------------------------------------

constexpr int NBLK  = 512;   // blocks for pass A / pass B (mapping must match)
constexpr int NPMAX = 512;   // max partitions (256 nodes each)

// Pass A: per-block partition histogram (LDS only).
__global__ __launch_bounds__(256) void passA_kernel(const int* __restrict__ dst, int E,
                                                    int* __restrict__ histG, int NP) {
    __shared__ int hist[NPMAX];
    for (int i = threadIdx.x; i < NP; i += 256) hist[i] = 0;
    __syncthreads();
    for (int e = blockIdx.x * 256 + threadIdx.x; e < E; e += NBLK * 256)
        atomicAdd(&hist[dst[e] >> 8], 1);
    __syncthreads();
    for (int p = threadIdx.x; p < NP; p += 256)
        histG[p * NBLK + blockIdx.x] = hist[p];   // p-major, block-minor
}

// ---- exclusive scan (3-kernel, 4096 items/block) ----
constexpr int SCAN_ITEMS = 16;
constexpr int SCAN_CHUNK = 256 * SCAN_ITEMS;  // 4096

__global__ __launch_bounds__(256) void scan1_kernel(const int* __restrict__ in,
                                                    int* __restrict__ outp,
                                                    int* __restrict__ blockSums, int n) {
    __shared__ int sh[256];
    int tbase = blockIdx.x * SCAN_CHUNK + threadIdx.x * SCAN_ITEMS;
    int vals[SCAN_ITEMS];
    int tsum = 0;
#pragma unroll
    for (int j = 0; j < SCAN_ITEMS; ++j) {
        int idx = tbase + j;
        int v = (idx < n) ? in[idx] : 0;
        vals[j] = tsum;
        tsum += v;
    }
    sh[threadIdx.x] = tsum;
    __syncthreads();
    for (int off = 1; off < 256; off <<= 1) {
        int v = (threadIdx.x >= off) ? sh[threadIdx.x - off] : 0;
        __syncthreads();
        sh[threadIdx.x] += v;
        __syncthreads();
    }
    int texcl = sh[threadIdx.x] - tsum;
    if (threadIdx.x == 255) blockSums[blockIdx.x] = sh[255];
#pragma unroll
    for (int j = 0; j < SCAN_ITEMS; ++j) {
        int idx = tbase + j;
        if (idx < n) outp[idx] = texcl + vals[j];
    }
}

__global__ void scan2_kernel(int* __restrict__ blockSums, int nb) {
    if (threadIdx.x == 0 && blockIdx.x == 0) {
        int run = 0;
        for (int i = 0; i < nb; ++i) { int v = blockSums[i]; blockSums[i] = run; run += v; }
    }
}

__global__ __launch_bounds__(256) void scan3_kernel(int* __restrict__ ptr,
                                                    const int* __restrict__ blockSums,
                                                    int n, int E) {
    int idx = blockIdx.x * blockDim.x + threadIdx.x;
    if (idx < n) ptr[idx] += blockSums[idx / SCAN_CHUNK];
    if (idx == 0) ptr[n] = E;   // sentinel
}

// Pass B: deterministic scatter to partition-sorted order. LDS cursors only.
// Record = (dstLocal<<17) | src  (src < 2^17, dstLocal < 256) -> 4 bytes.
__global__ __launch_bounds__(256) void passB_kernel(const int* __restrict__ src,
                                                    const int* __restrict__ dst,
                                                    const int* __restrict__ histS,
                                                    unsigned* __restrict__ recP,
                                                    int E, int NP) {
    __shared__ int cur[NPMAX];
    for (int i = threadIdx.x; i < NP; i += 256) cur[i] = histS[i * NBLK + blockIdx.x];
    __syncthreads();
    for (int e = blockIdx.x * 256 + threadIdx.x; e < E; e += NBLK * 256) {
        int s = src[e], d = dst[e];
        int slot = atomicAdd(&cur[d >> 8], 1);   // LDS atomic, block-private run
        recP[slot] = ((unsigned)(d & 255) << 17) | (unsigned)s;
    }
}

// Pass C: one block per partition. Per-node degree count (LDS) -> dinv ->
// LDS scan -> rowptr slice -> scatter src into per-node CSR order.
__global__ __launch_bounds__(256) void passC_kernel(const unsigned* __restrict__ recP,
                                                    const int* __restrict__ histS,
                                                    int* __restrict__ rec,
                                                    int* __restrict__ rowptr,
                                                    float* __restrict__ dinv,
                                                    int N, int E) {
    __shared__ int cntL[256];
    __shared__ int sh[256];
    const int p = blockIdx.x;
    const int S    = histS[p * NBLK];
    const int Eend = histS[(p + 1) * NBLK];   // sentinel covers last partition
    cntL[threadIdx.x] = 0;
    __syncthreads();
    for (int i = S + threadIdx.x; i < Eend; i += 256)
        atomicAdd(&cntL[recP[i] >> 17], 1);
    __syncthreads();
    int v = cntL[threadIdx.x];                // this node's degree
    int node = p * 256 + threadIdx.x;
    if (node < N) dinv[node] = rsqrtf((float)v + 1.0f);  // +1 self-loop
    sh[threadIdx.x] = v;
    __syncthreads();
    for (int off = 1; off < 256; off <<= 1) {
        int u = (threadIdx.x >= off) ? sh[threadIdx.x - off] : 0;
        __syncthreads();
        sh[threadIdx.x] += u;
        __syncthreads();
    }
    int excl = sh[threadIdx.x] - v;           // exclusive within partition
    if (node < N) rowptr[node] = S + excl;
    if (p == 0 && threadIdx.x == 0) rowptr[N] = E;
    __syncthreads();
    cntL[threadIdx.x] = S + excl;             // reuse as cursor
    __syncthreads();
    for (int i = S + threadIdx.x; i < Eend; i += 256) {
        unsigned r = recP[i];
        int slot = atomicAdd(&cntL[r >> 17], 1);
        rec[slot] = (int)(r & 0x1FFFFu);
    }
}

// ---------------------------------------------------------------------------
// Register-tiled GEMM with fused row scale: out[row] = (A[row] @ W) * dinv[row].
// Block = 256 thr = 16x16 grid, 4x4 outputs/thread => 64 rows x 64 cols.
// ---------------------------------------------------------------------------
template <int K, int M>
__global__ __launch_bounds__(256) void gemm_kernel(const float* __restrict__ A,
                                                   const float* __restrict__ W,
                                                   const float* __restrict__ dinv,
                                                   float* __restrict__ out, int N) {
    constexpr int KC = 64;
    constexpr int SA = 68;
    __shared__ float Ws[K * M];
    __shared__ float As[KC * SA];   // As[k][row]
    for (int i = threadIdx.x; i < K * M; i += 256) Ws[i] = W[i];

    const int tr = threadIdx.x & 15;
    const int tc = threadIdx.x >> 4;
    const int r0 = tr * 4, c0 = tc * 4;
    const int row0 = blockIdx.x * 64;
    const bool colAct = (c0 < M);

    float acc[4][4] = {};

    for (int k0 = 0; k0 < K; k0 += KC) {
        __syncthreads();
        {
            const int kq = threadIdx.x & 15;
            const int rr = threadIdx.x >> 4;
#pragma unroll
            for (int p = 0; p < 4; ++p) {
                int row = rr + p * 16;
                int grow = row0 + row;
                float4 v = make_float4(0.f, 0.f, 0.f, 0.f);
                if (grow < N)
                    v = *reinterpret_cast<const float4*>(&A[(size_t)grow * K + k0 + kq * 4]);
                As[(kq * 4 + 0) * SA + row] = v.x;
                As[(kq * 4 + 1) * SA + row] = v.y;
                As[(kq * 4 + 2) * SA + row] = v.z;
                As[(kq * 4 + 3) * SA + row] = v.w;
            }
        }
        __syncthreads();
        if (colAct) {
#pragma unroll 8
            for (int kk = 0; kk < KC; ++kk) {
                float4 a = *reinterpret_cast<const float4*>(&As[kk * SA + r0]);
                float4 b = *reinterpret_cast<const float4*>(&Ws[(k0 + kk) * M + c0]);
                acc[0][0] = fmaf(a.x, b.x, acc[0][0]); acc[0][1] = fmaf(a.x, b.y, acc[0][1]);
                acc[0][2] = fmaf(a.x, b.z, acc[0][2]); acc[0][3] = fmaf(a.x, b.w, acc[0][3]);
                acc[1][0] = fmaf(a.y, b.x, acc[1][0]); acc[1][1] = fmaf(a.y, b.y, acc[1][1]);
                acc[1][2] = fmaf(a.y, b.z, acc[1][2]); acc[1][3] = fmaf(a.y, b.w, acc[1][3]);
                acc[2][0] = fmaf(a.z, b.x, acc[2][0]); acc[2][1] = fmaf(a.z, b.y, acc[2][1]);
                acc[2][2] = fmaf(a.z, b.z, acc[2][2]); acc[2][3] = fmaf(a.z, b.w, acc[2][3]);
                acc[3][0] = fmaf(a.w, b.x, acc[3][0]); acc[3][1] = fmaf(a.w, b.y, acc[3][1]);
                acc[3][2] = fmaf(a.w, b.z, acc[3][2]); acc[3][3] = fmaf(a.w, b.w, acc[3][3]);
            }
        }
    }

    if (colAct) {
#pragma unroll
        for (int i = 0; i < 4; ++i) {
            int grow = row0 + r0 + i;
            if (grow < N) {
                float s = dinv[grow];
                float4 o = make_float4(acc[i][0] * s, acc[i][1] * s,
                                       acc[i][2] * s, acc[i][3] * s);
                *reinterpret_cast<float4*>(&out[(size_t)grow * M + c0]) = o;
            }
        }
    }
}

// ---------------------------------------------------------------------------
// Gather aggregation, shfl-sourced, WAVE-CONVERGENT: one wave per node.
// Coalesced 64-wide rec load -> srcs in registers; gather addresses via
// __shfl. Main loop = G full groups of 16 (G wave-uniform -> lockstep shfl,
// 16 independent row-gathers in flight). Tail = uniform step count with
// clamped shfl index + predicated accumulate (shfl never inside divergence).
// out[n] = relu( dinv[n] * ( sum_e t'[src_e] + t'[n] ) )
// ---------------------------------------------------------------------------
template <int D>
__global__ __launch_bounds__(256) void agg_kernel(const float* __restrict__ t,
                                                  const int* __restrict__ rowptr,
                                                  const int* __restrict__ rec,
                                                  const float* __restrict__ dinv,
                                                  float* __restrict__ out, int N) {
    int n = blockIdx.x * 4 + (threadIdx.x >> 6);
    if (n >= N) return;
    const int lane = threadIdx.x & 63;
    const int q  = lane >> 4;          // quarter 0..3
    const int fl = (lane & 15) * 4;    // feature base
    const bool act = (fl < D);
    const int beg = rowptr[n], end = rowptr[n + 1];
    const int deg = end - beg;

    float ax = 0.f, ay = 0.f, az = 0.f, aw = 0.f;
    if (q == 0 && act) {   // self-loop: t'[n]
        float4 v = *reinterpret_cast<const float4*>(&t[(size_t)n * D + fl]);
        ax = v.x; ay = v.y; az = v.z; aw = v.w;
    }

    for (int base = 0; base < deg; base += 64) {
        int idx = base + lane;
        int rc = (idx < deg) ? rec[beg + idx] : 0;   // coalesced, 64 edges/load
        const int lim = min(deg - base, 64);         // wave-uniform
        const int G = lim >> 4;                      // full groups of 16 (uniform)
        int j = q;
        for (int g = 0; g < G; ++g, j += 16) {       // lockstep across all quarters
            int s0 = __shfl(rc, j);
            int s1 = __shfl(rc, j + 4);
            int s2 = __shfl(rc, j + 8);
            int s3 = __shfl(rc, j + 12);
            if (act) {
                float4 v0 = *reinterpret_cast<const float4*>(&t[(size_t)s0 * D + fl]);
                float4 v1 = *reinterpret_cast<const float4*>(&t[(size_t)s1 * D + fl]);
                float4 v2 = *reinterpret_cast<const float4*>(&t[(size_t)s2 * D + fl]);
                float4 v3 = *reinterpret_cast<const float4*>(&t[(size_t)s3 * D + fl]);
                ax += v0.x; ay += v0.y; az += v0.z; aw += v0.w;
                ax += v1.x; ay += v1.y; az += v1.z; aw += v1.w;
                ax += v2.x; ay += v2.y; az += v2.z; aw += v2.w;
                ax += v3.x; ay += v3.y; az += v3.z; aw += v3.w;
            }
        }
        // tail: r in [0,16); uniform step count, shfl outside divergence
        const int r = lim - (G << 4);
        const int steps = (r + 3) >> 2;              // wave-uniform 0..4
        for (int s = 0; s < steps; ++s, j += 4) {
            int jj = (j < lim) ? j : 0;              // clamp for convergent shfl
            int sn = __shfl(rc, jj);
            if (act && j < lim) {
                float4 v = *reinterpret_cast<const float4*>(&t[(size_t)sn * D + fl]);
                ax += v.x; ay += v.y; az += v.z; aw += v.w;
            }
        }
    }

    ax += __shfl_xor(ax, 16); ay += __shfl_xor(ay, 16);
    az += __shfl_xor(az, 16); aw += __shfl_xor(aw, 16);
    ax += __shfl_xor(ax, 32); ay += __shfl_xor(ay, 32);
    az += __shfl_xor(az, 32); aw += __shfl_xor(aw, 32);

    if (q == 0 && act) {
        float di = dinv[n];
        float4 o = make_float4(fmaxf(di * ax, 0.f), fmaxf(di * ay, 0.f),
                               fmaxf(di * az, 0.f), fmaxf(di * aw, 0.f));
        *reinterpret_cast<float4*>(&out[(size_t)n * D + fl]) = o;
    }
}

extern "C" void kernel_launch(void* const* d_in, const int* in_sizes, int n_in,
                              void* d_out, int out_size, void* d_ws, size_t ws_size,
                              hipStream_t stream) {
    const float* x  = (const float*)d_in[0];
    const int*   ei = (const int*)d_in[1];   // [2, E] row-major, int32
    const float* W0 = (const float*)d_in[2]; // [128,64]
    const float* W1 = (const float*)d_in[3]; // [64,64]
    const float* W2 = (const float*)d_in[4]; // [64,40]
    float* out = (float*)d_out;

    const int N = in_sizes[0] / 128;
    const int E = in_sizes[1] / 2;
    const int* src = ei;
    const int* dst = ei + E;
    const int NP = (N + 255) / 256;          // 391 partitions of 256 nodes
    const int histItems = NP * NBLK;         // 200192

    char* w = (char*)d_ws;
    size_t off = 0;
    auto alloc = [&](size_t bytes) {
        void* p = w + off;
        off += bytes;
        off = (off + 255) & ~(size_t)255;
        return p;
    };
    float*    dinv   = (float*)alloc((size_t)N * 4);
    int*      histG  = (int*)alloc((size_t)histItems * 4);
    int*      histS  = (int*)alloc((size_t)(histItems + 1) * 4);
    int*      rowptr = (int*)alloc((size_t)(N + 1) * 4);
    int*      bsums  = (int*)alloc(4096);
    int*      rec    = (int*)alloc((size_t)E * 4);     // per-node CSR (persists)
    float*    B2     = (float*)alloc((size_t)N * 64 * 4);
    float*    B1     = (float*)alloc((size_t)N * 64 * 4);
    unsigned* recP   = (unsigned*)B1;   // partition-sorted recs, dead after passC

    // --- CSR build (counting sort, zero global atomics; reused by 3 layers) ---
    passA_kernel<<<NBLK, 256, 0, stream>>>(dst, E, histG, NP);
    const int nCh = (histItems + SCAN_CHUNK - 1) / SCAN_CHUNK;
    scan1_kernel<<<nCh, 256, 0, stream>>>(histG, histS, bsums, histItems);
    scan2_kernel<<<1, 64, 0, stream>>>(bsums, nCh);
    scan3_kernel<<<(histItems + 255) / 256, 256, 0, stream>>>(histS, bsums, histItems, E);
    passB_kernel<<<NBLK, 256, 0, stream>>>(src, dst, histS, recP, E, NP);
    passC_kernel<<<NP, 256, 0, stream>>>(recP, histS, rec, rowptr, dinv, N, E);

    const int gemmGrid = (N + 63) / 64;

    // --- layer 0 ---
    gemm_kernel<128, 64><<<gemmGrid, 256, 0, stream>>>(x, W0, dinv, B1, N);
    agg_kernel<64><<<(N + 3) / 4, 256, 0, stream>>>(B1, rowptr, rec, dinv, B2, N);

    // --- layer 1 ---
    gemm_kernel<64, 64><<<gemmGrid, 256, 0, stream>>>(B2, W1, dinv, B1, N);
    agg_kernel<64><<<(N + 3) / 4, 256, 0, stream>>>(B1, rowptr, rec, dinv, B2, N);

    // --- layer 2 ---
    gemm_kernel<64, 40><<<gemmGrid, 256, 0, stream>>>(B2, W2, dinv, B1, N);
    agg_kernel<40><<<(N + 3) / 4, 256, 0, stream>>>(B1, rowptr, rec, dinv, out, N);
}

// Round 11
// 342.059 us; speedup vs baseline: 5.3386x; 1.1402x over previous
//
#include <hip/hip_runtime.h>
#include <hip/hip_fp16.h>
#include <cstddef>

// ---------------------------------------------------------------------------
// GCN: out = relu(Â relu(Â relu(Â (x W0)) W1) W2),  Â = D^-1/2 (A+I) D^-1/2
// R11: t' (the randomly-gathered buffer) stored in FP16 -> halves the
// per-XCD L2 fill traffic that bounds agg (FETCH was 8 XCD x 25.6 MB).
// GEMM epilogue converts+scales to fp16; agg accumulates fp32. CSR via
// atomic-free counting sort (R7); norm factored out of edge loop (R8).
// ---------------------------------------------------------------------------

constexpr int NBLK  = 512;   // blocks for pass A / pass B (mapping must match)
constexpr int NPMAX = 512;   // max partitions (256 nodes each)

// Pass A: per-block partition histogram (LDS only).
__global__ __launch_bounds__(256) void passA_kernel(const int* __restrict__ dst, int E,
                                                    int* __restrict__ histG, int NP) {
    __shared__ int hist[NPMAX];
    for (int i = threadIdx.x; i < NP; i += 256) hist[i] = 0;
    __syncthreads();
    for (int e = blockIdx.x * 256 + threadIdx.x; e < E; e += NBLK * 256)
        atomicAdd(&hist[dst[e] >> 8], 1);
    __syncthreads();
    for (int p = threadIdx.x; p < NP; p += 256)
        histG[p * NBLK + blockIdx.x] = hist[p];   // p-major, block-minor
}

// ---- exclusive scan (3-kernel, 4096 items/block) ----
constexpr int SCAN_ITEMS = 16;
constexpr int SCAN_CHUNK = 256 * SCAN_ITEMS;  // 4096

__global__ __launch_bounds__(256) void scan1_kernel(const int* __restrict__ in,
                                                    int* __restrict__ outp,
                                                    int* __restrict__ blockSums, int n) {
    __shared__ int sh[256];
    int tbase = blockIdx.x * SCAN_CHUNK + threadIdx.x * SCAN_ITEMS;
    int vals[SCAN_ITEMS];
    int tsum = 0;
#pragma unroll
    for (int j = 0; j < SCAN_ITEMS; ++j) {
        int idx = tbase + j;
        int v = (idx < n) ? in[idx] : 0;
        vals[j] = tsum;
        tsum += v;
    }
    sh[threadIdx.x] = tsum;
    __syncthreads();
    for (int off = 1; off < 256; off <<= 1) {
        int v = (threadIdx.x >= off) ? sh[threadIdx.x - off] : 0;
        __syncthreads();
        sh[threadIdx.x] += v;
        __syncthreads();
    }
    int texcl = sh[threadIdx.x] - tsum;
    if (threadIdx.x == 255) blockSums[blockIdx.x] = sh[255];
#pragma unroll
    for (int j = 0; j < SCAN_ITEMS; ++j) {
        int idx = tbase + j;
        if (idx < n) outp[idx] = texcl + vals[j];
    }
}

__global__ void scan2_kernel(int* __restrict__ blockSums, int nb) {
    if (threadIdx.x == 0 && blockIdx.x == 0) {
        int run = 0;
        for (int i = 0; i < nb; ++i) { int v = blockSums[i]; blockSums[i] = run; run += v; }
    }
}

__global__ __launch_bounds__(256) void scan3_kernel(int* __restrict__ ptr,
                                                    const int* __restrict__ blockSums,
                                                    int n, int E) {
    int idx = blockIdx.x * blockDim.x + threadIdx.x;
    if (idx < n) ptr[idx] += blockSums[idx / SCAN_CHUNK];
    if (idx == 0) ptr[n] = E;   // sentinel
}

// Pass B: deterministic scatter to partition-sorted order. LDS cursors only.
// Record = (dstLocal<<17) | src  (src < 2^17, dstLocal < 256) -> 4 bytes.
__global__ __launch_bounds__(256) void passB_kernel(const int* __restrict__ src,
                                                    const int* __restrict__ dst,
                                                    const int* __restrict__ histS,
                                                    unsigned* __restrict__ recP,
                                                    int E, int NP) {
    __shared__ int cur[NPMAX];
    for (int i = threadIdx.x; i < NP; i += 256) cur[i] = histS[i * NBLK + blockIdx.x];
    __syncthreads();
    for (int e = blockIdx.x * 256 + threadIdx.x; e < E; e += NBLK * 256) {
        int s = src[e], d = dst[e];
        int slot = atomicAdd(&cur[d >> 8], 1);   // LDS atomic, block-private run
        recP[slot] = ((unsigned)(d & 255) << 17) | (unsigned)s;
    }
}

// Pass C: one block per partition. Per-node degree count (LDS) -> dinv ->
// LDS scan -> rowptr slice -> scatter src into per-node CSR order.
__global__ __launch_bounds__(256) void passC_kernel(const unsigned* __restrict__ recP,
                                                    const int* __restrict__ histS,
                                                    int* __restrict__ rec,
                                                    int* __restrict__ rowptr,
                                                    float* __restrict__ dinv,
                                                    int N, int E) {
    __shared__ int cntL[256];
    __shared__ int sh[256];
    const int p = blockIdx.x;
    const int S    = histS[p * NBLK];
    const int Eend = histS[(p + 1) * NBLK];   // sentinel covers last partition
    cntL[threadIdx.x] = 0;
    __syncthreads();
    for (int i = S + threadIdx.x; i < Eend; i += 256)
        atomicAdd(&cntL[recP[i] >> 17], 1);
    __syncthreads();
    int v = cntL[threadIdx.x];                // this node's degree
    int node = p * 256 + threadIdx.x;
    if (node < N) dinv[node] = rsqrtf((float)v + 1.0f);  // +1 self-loop
    sh[threadIdx.x] = v;
    __syncthreads();
    for (int off = 1; off < 256; off <<= 1) {
        int u = (threadIdx.x >= off) ? sh[threadIdx.x - off] : 0;
        __syncthreads();
        sh[threadIdx.x] += u;
        __syncthreads();
    }
    int excl = sh[threadIdx.x] - v;           // exclusive within partition
    if (node < N) rowptr[node] = S + excl;
    if (p == 0 && threadIdx.x == 0) rowptr[N] = E;
    __syncthreads();
    cntL[threadIdx.x] = S + excl;             // reuse as cursor
    __syncthreads();
    for (int i = S + threadIdx.x; i < Eend; i += 256) {
        unsigned r = recP[i];
        int slot = atomicAdd(&cntL[r >> 17], 1);
        rec[slot] = (int)(r & 0x1FFFFu);
    }
}

// ---------------------------------------------------------------------------
// Register-tiled GEMM, fused row scale + FP16 convert:
// outH[row] = (__half)( (A[row] @ W) * dinv[row] ).
// Block = 256 thr = 16x16 grid, 4x4 outputs/thread => 64 rows x 64 cols.
// ---------------------------------------------------------------------------
template <int K, int M>
__global__ __launch_bounds__(256) void gemm_kernel(const float* __restrict__ A,
                                                   const float* __restrict__ W,
                                                   const float* __restrict__ dinv,
                                                   __half* __restrict__ outH, int N) {
    constexpr int KC = 64;
    constexpr int SA = 68;
    __shared__ float Ws[K * M];
    __shared__ float As[KC * SA];   // As[k][row]
    for (int i = threadIdx.x; i < K * M; i += 256) Ws[i] = W[i];

    const int tr = threadIdx.x & 15;
    const int tc = threadIdx.x >> 4;
    const int r0 = tr * 4, c0 = tc * 4;
    const int row0 = blockIdx.x * 64;
    const bool colAct = (c0 < M);

    float acc[4][4] = {};

    for (int k0 = 0; k0 < K; k0 += KC) {
        __syncthreads();
        {
            const int kq = threadIdx.x & 15;
            const int rr = threadIdx.x >> 4;
#pragma unroll
            for (int p = 0; p < 4; ++p) {
                int row = rr + p * 16;
                int grow = row0 + row;
                float4 v = make_float4(0.f, 0.f, 0.f, 0.f);
                if (grow < N)
                    v = *reinterpret_cast<const float4*>(&A[(size_t)grow * K + k0 + kq * 4]);
                As[(kq * 4 + 0) * SA + row] = v.x;
                As[(kq * 4 + 1) * SA + row] = v.y;
                As[(kq * 4 + 2) * SA + row] = v.z;
                As[(kq * 4 + 3) * SA + row] = v.w;
            }
        }
        __syncthreads();
        if (colAct) {
#pragma unroll 8
            for (int kk = 0; kk < KC; ++kk) {
                float4 a = *reinterpret_cast<const float4*>(&As[kk * SA + r0]);
                float4 b = *reinterpret_cast<const float4*>(&Ws[(k0 + kk) * M + c0]);
                acc[0][0] = fmaf(a.x, b.x, acc[0][0]); acc[0][1] = fmaf(a.x, b.y, acc[0][1]);
                acc[0][2] = fmaf(a.x, b.z, acc[0][2]); acc[0][3] = fmaf(a.x, b.w, acc[0][3]);
                acc[1][0] = fmaf(a.y, b.x, acc[1][0]); acc[1][1] = fmaf(a.y, b.y, acc[1][1]);
                acc[1][2] = fmaf(a.y, b.z, acc[1][2]); acc[1][3] = fmaf(a.y, b.w, acc[1][3]);
                acc[2][0] = fmaf(a.z, b.x, acc[2][0]); acc[2][1] = fmaf(a.z, b.y, acc[2][1]);
                acc[2][2] = fmaf(a.z, b.z, acc[2][2]); acc[2][3] = fmaf(a.z, b.w, acc[2][3]);
                acc[3][0] = fmaf(a.w, b.x, acc[3][0]); acc[3][1] = fmaf(a.w, b.y, acc[3][1]);
                acc[3][2] = fmaf(a.w, b.z, acc[3][2]); acc[3][3] = fmaf(a.w, b.w, acc[3][3]);
            }
        }
    }

    if (colAct) {
#pragma unroll
        for (int i = 0; i < 4; ++i) {
            int grow = row0 + r0 + i;
            if (grow < N) {
                float s = dinv[grow];
                __half2 p0 = __floats2half2_rn(acc[i][0] * s, acc[i][1] * s);
                __half2 p1 = __floats2half2_rn(acc[i][2] * s, acc[i][3] * s);
                uint2 o;
                o.x = *reinterpret_cast<unsigned*>(&p0);
                o.y = *reinterpret_cast<unsigned*>(&p1);
                *reinterpret_cast<uint2*>(&outH[(size_t)grow * M + c0]) = o;
            }
        }
    }
}

// ---------------------------------------------------------------------------
// Gather aggregation from FP16 t', shfl-sourced, wave-convergent.
// One wave per node; 16-lane quarter per edge, lane = 4 fp16 features (8B).
// Main loop = G full groups of 16 edges (lockstep shfl, 16 gathers in
// flight); tail = uniform steps, clamped shfl + predicated accumulate.
// out[n] = relu( dinv[n] * ( sum_e t'[src_e] + t'[n] ) )   (fp32 out)
// ---------------------------------------------------------------------------
template <int D>
__global__ __launch_bounds__(256) void agg_kernel(const __half* __restrict__ t,
                                                  const int* __restrict__ rowptr,
                                                  const int* __restrict__ rec,
                                                  const float* __restrict__ dinv,
                                                  float* __restrict__ out, int N) {
    int n = blockIdx.x * 4 + (threadIdx.x >> 6);
    if (n >= N) return;
    const int lane = threadIdx.x & 63;
    const int q  = lane >> 4;          // quarter 0..3
    const int fl = (lane & 15) * 4;    // feature base
    const bool act = (fl < D);
    const int beg = rowptr[n], end = rowptr[n + 1];
    const int deg = end - beg;

    float ax = 0.f, ay = 0.f, az = 0.f, aw = 0.f;
    if (q == 0 && act) {   // self-loop: t'[n]
        uint2 raw = *reinterpret_cast<const uint2*>(&t[(size_t)n * D + fl]);
        float2 f0 = __half22float2(*reinterpret_cast<const __half2*>(&raw.x));
        float2 f1 = __half22float2(*reinterpret_cast<const __half2*>(&raw.y));
        ax = f0.x; ay = f0.y; az = f1.x; aw = f1.y;
    }

    for (int base = 0; base < deg; base += 64) {
        int idx = base + lane;
        int rc = (idx < deg) ? rec[beg + idx] : 0;   // coalesced, 64 edges/load
        const int lim = min(deg - base, 64);         // wave-uniform
        const int G = lim >> 4;                      // full groups of 16 (uniform)
        int j = q;
        for (int g = 0; g < G; ++g, j += 16) {       // lockstep across quarters
            int s0 = __shfl(rc, j);
            int s1 = __shfl(rc, j + 4);
            int s2 = __shfl(rc, j + 8);
            int s3 = __shfl(rc, j + 12);
            if (act) {
                uint2 r0 = *reinterpret_cast<const uint2*>(&t[(size_t)s0 * D + fl]);
                uint2 r1 = *reinterpret_cast<const uint2*>(&t[(size_t)s1 * D + fl]);
                uint2 r2 = *reinterpret_cast<const uint2*>(&t[(size_t)s2 * D + fl]);
                uint2 r3 = *reinterpret_cast<const uint2*>(&t[(size_t)s3 * D + fl]);
                float2 a0 = __half22float2(*reinterpret_cast<const __half2*>(&r0.x));
                float2 b0 = __half22float2(*reinterpret_cast<const __half2*>(&r0.y));
                float2 a1 = __half22float2(*reinterpret_cast<const __half2*>(&r1.x));
                float2 b1 = __half22float2(*reinterpret_cast<const __half2*>(&r1.y));
                float2 a2 = __half22float2(*reinterpret_cast<const __half2*>(&r2.x));
                float2 b2 = __half22float2(*reinterpret_cast<const __half2*>(&r2.y));
                float2 a3 = __half22float2(*reinterpret_cast<const __half2*>(&r3.x));
                float2 b3 = __half22float2(*reinterpret_cast<const __half2*>(&r3.y));
                ax += a0.x; ay += a0.y; az += b0.x; aw += b0.y;
                ax += a1.x; ay += a1.y; az += b1.x; aw += b1.y;
                ax += a2.x; ay += a2.y; az += b2.x; aw += b2.y;
                ax += a3.x; ay += a3.y; az += b3.x; aw += b3.y;
            }
        }
        // tail: r in [0,16); uniform step count, shfl outside divergence
        const int r = lim - (G << 4);
        const int steps = (r + 3) >> 2;              // wave-uniform 0..4
        for (int s = 0; s < steps; ++s, j += 4) {
            int jj = (j < lim) ? j : 0;              // clamp for convergent shfl
            int sn = __shfl(rc, jj);
            if (act && j < lim) {
                uint2 rr = *reinterpret_cast<const uint2*>(&t[(size_t)sn * D + fl]);
                float2 f0 = __half22float2(*reinterpret_cast<const __half2*>(&rr.x));
                float2 f1 = __half22float2(*reinterpret_cast<const __half2*>(&rr.y));
                ax += f0.x; ay += f0.y; az += f1.x; aw += f1.y;
            }
        }
    }

    ax += __shfl_xor(ax, 16); ay += __shfl_xor(ay, 16);
    az += __shfl_xor(az, 16); aw += __shfl_xor(aw, 16);
    ax += __shfl_xor(ax, 32); ay += __shfl_xor(ay, 32);
    az += __shfl_xor(az, 32); aw += __shfl_xor(aw, 32);

    if (q == 0 && act) {
        float di = dinv[n];
        float4 o = make_float4(fmaxf(di * ax, 0.f), fmaxf(di * ay, 0.f),
                               fmaxf(di * az, 0.f), fmaxf(di * aw, 0.f));
        *reinterpret_cast<float4*>(&out[(size_t)n * D + fl]) = o;
    }
}

extern "C" void kernel_launch(void* const* d_in, const int* in_sizes, int n_in,
                              void* d_out, int out_size, void* d_ws, size_t ws_size,
                              hipStream_t stream) {
    const float* x  = (const float*)d_in[0];
    const int*   ei = (const int*)d_in[1];   // [2, E] row-major, int32
    const float* W0 = (const float*)d_in[2]; // [128,64]
    const float* W1 = (const float*)d_in[3]; // [64,64]
    const float* W2 = (const float*)d_in[4]; // [64,40]
    float* out = (float*)d_out;

    const int N = in_sizes[0] / 128;
    const int E = in_sizes[1] / 2;
    const int* src = ei;
    const int* dst = ei + E;
    const int NP = (N + 255) / 256;          // 391 partitions of 256 nodes
    const int histItems = NP * NBLK;         // 200192

    char* w = (char*)d_ws;
    size_t off = 0;
    auto alloc = [&](size_t bytes) {
        void* p = w + off;
        off += bytes;
        off = (off + 255) & ~(size_t)255;
        return p;
    };
    float*    dinv   = (float*)alloc((size_t)N * 4);
    int*      histG  = (int*)alloc((size_t)histItems * 4);
    int*      histS  = (int*)alloc((size_t)(histItems + 1) * 4);
    int*      rowptr = (int*)alloc((size_t)(N + 1) * 4);
    int*      bsums  = (int*)alloc(4096);
    int*      rec    = (int*)alloc((size_t)E * 4);     // per-node CSR (persists)
    float*    B2     = (float*)alloc((size_t)N * 64 * 4);   // fp32 agg-out / gemm-in
    __half*   tP     = (__half*)alloc((size_t)N * 64 * 2);  // fp16 t' (gathered)
    unsigned* recP   = (unsigned*)tP;   // partition-sorted recs, dead before gemm0

    // --- CSR build (counting sort, zero global atomics; reused by 3 layers) ---
    passA_kernel<<<NBLK, 256, 0, stream>>>(dst, E, histG, NP);
    const int nCh = (histItems + SCAN_CHUNK - 1) / SCAN_CHUNK;
    scan1_kernel<<<nCh, 256, 0, stream>>>(histG, histS, bsums, histItems);
    scan2_kernel<<<1, 64, 0, stream>>>(bsums, nCh);
    scan3_kernel<<<(histItems + 255) / 256, 256, 0, stream>>>(histS, bsums, histItems, E);
    passB_kernel<<<NBLK, 256, 0, stream>>>(src, dst, histS, recP, E, NP);
    passC_kernel<<<NP, 256, 0, stream>>>(recP, histS, rec, rowptr, dinv, N, E);

    const int gemmGrid = (N + 63) / 64;

    // --- layer 0 ---
    gemm_kernel<128, 64><<<gemmGrid, 256, 0, stream>>>(x, W0, dinv, tP, N);
    agg_kernel<64><<<(N + 3) / 4, 256, 0, stream>>>(tP, rowptr, rec, dinv, B2, N);

    // --- layer 1 ---
    gemm_kernel<64, 64><<<gemmGrid, 256, 0, stream>>>(B2, W1, dinv, tP, N);
    agg_kernel<64><<<(N + 3) / 4, 256, 0, stream>>>(tP, rowptr, rec, dinv, B2, N);

    // --- layer 2 ---
    gemm_kernel<64, 40><<<gemmGrid, 256, 0, stream>>>(B2, W2, dinv, tP, N);
    agg_kernel<40><<<(N + 3) / 4, 256, 0, stream>>>(tP, rowptr, rec, dinv, out, N);
}